// Round 1
// baseline (1050.036 us; speedup 1.0000x reference)
//
#include <hip/hip_runtime.h>
#include <cstdint>
#include <cstddef>

#define INDIM 256
#define NEG 0.2f

// ---------------- GEMM: Y[M,NC] = X[M,K] @ W[K,NC], block = NC threads, BM rows ----------------
template<int K, int NC, int BM>
__global__ __launch_bounds__(NC) void gemm_rows(const float* __restrict__ X,
                                                const float* __restrict__ W,
                                                float* __restrict__ Y, int M) {
  __shared__ float xs[BM][K];
  const int tid = threadIdx.x;
  const int row0 = blockIdx.x * BM;
  for (int i = tid; i < BM * K; i += NC) {
    int r = i / K, c = i - r * K;
    int gr = row0 + r;
    xs[r][c] = (gr < M) ? X[(size_t)gr * K + c] : 0.f;
  }
  __syncthreads();
  float acc[BM];
#pragma unroll
  for (int r = 0; r < BM; ++r) acc[r] = 0.f;
  const int j = tid;
  for (int k = 0; k < K; ++k) {
    float w = W[(size_t)k * NC + j];
#pragma unroll
    for (int r = 0; r < BM; ++r) acc[r] = fmaf(xs[r][k], w, acc[r]);
  }
#pragma unroll
  for (int r = 0; r < BM; ++r) {
    int gr = row0 + r;
    if (gr < M) Y[(size_t)gr * NC + j] = acc[r];
  }
}

// ---------------- per-(node,head) attention dots: s = h . att_src, d = h . att_dst ----------------
__global__ __launch_bounds__(64) void sd_kernel(const float* __restrict__ H,
                                                const float* __restrict__ As,
                                                const float* __restrict__ Ad,
                                                float* __restrict__ S, float* __restrict__ D,
                                                int NH) {
  int b = blockIdx.x;            // n*NH + h
  int h = b % NH;
  int lane = threadIdx.x;        // 64
  const float* hr = H + (size_t)b * 128;   // [N, NH*128] row-major => offset b*128
  float x0 = hr[lane], x1 = hr[lane + 64];
  const float* as = As + h * 128;
  const float* ad = Ad + h * 128;
  float vs = x0 * as[lane] + x1 * as[lane + 64];
  float vd = x0 * ad[lane] + x1 * ad[lane + 64];
#pragma unroll
  for (int o = 32; o; o >>= 1) { vs += __shfl_down(vs, o); vd += __shfl_down(vd, o); }
  if (lane == 0) { S[b] = vs; D[b] = vd; }
}

// ---------------- CSR build ----------------
__global__ void deg_kernel(const int* __restrict__ edst, int E, int Etot, int* __restrict__ deg) {
  int e = blockIdx.x * blockDim.x + threadIdx.x;
  if (e >= Etot) return;
  int dn = (e < E) ? edst[e] : (e - E);
  atomicAdd(&deg[dn], 1);
}

__global__ __launch_bounds__(1024) void scan_kernel(const int* __restrict__ deg,
                                                    int* __restrict__ rowptr,
                                                    int* __restrict__ cursor, int n) {
  __shared__ int tmp[1024];
  __shared__ int carry_s;
  int tid = threadIdx.x;
  if (tid == 0) { carry_s = 0; rowptr[0] = 0; }
  __syncthreads();
  for (int base = 0; base < n; base += 1024) {
    int i = base + tid;
    int v = (i < n) ? deg[i] : 0;
    tmp[tid] = v;
    __syncthreads();
    for (int ofs = 1; ofs < 1024; ofs <<= 1) {
      int t = (tid >= ofs) ? tmp[tid - ofs] : 0;
      __syncthreads();
      tmp[tid] += t;
      __syncthreads();
    }
    int incl = tmp[tid] + carry_s;
    if (i < n) { rowptr[i + 1] = incl; cursor[i] = incl - v; }
    __syncthreads();
    if (tid == 1023) carry_s = incl;
    __syncthreads();
  }
}

__global__ void fill_kernel(const int* __restrict__ esrc, const int* __restrict__ edst,
                            int E, int Etot, int* __restrict__ cursor,
                            int* __restrict__ csr_src, int* __restrict__ csr_eid) {
  int e = blockIdx.x * blockDim.x + threadIdx.x;
  if (e >= Etot) return;
  int s, dn;
  if (e < E) { s = esrc[e]; dn = edst[e]; } else { s = dn = e - E; }
  int pos = atomicAdd(&cursor[dn], 1);
  csr_src[pos] = s;
  csr_eid[pos] = e;
}

// ---------------- edge softmax (no max-shift: mathematically identical, fp32-safe here) ----------------
template<int H>
__global__ void edge_exp_kernel(const float* __restrict__ S, const float* __restrict__ D,
                                const int* __restrict__ esrc, const int* __restrict__ edst,
                                int E, int Etot, float* __restrict__ exbuf,
                                float* __restrict__ denom) {
  int e = blockIdx.x * blockDim.x + threadIdx.x;
  if (e >= Etot) return;
  int sn, dn;
  if (e < E) { sn = esrc[e]; dn = edst[e]; } else { sn = dn = e - E; }
#pragma unroll
  for (int h = 0; h < H; ++h) {
    float v = S[sn * H + h] + D[dn * H + h];
    v = (v > 0.f) ? v : NEG * v;
    float ex = expf(v);
    exbuf[(size_t)e * H + h] = ex;
    atomicAdd(&denom[dn * H + h], ex);
  }
}

template<int H>
__global__ void alpha_kernel(const float* __restrict__ exbuf, const float* __restrict__ denom,
                             const int* __restrict__ edst, int E, int Etot,
                             float* __restrict__ alpha) {
  int e = blockIdx.x * blockDim.x + threadIdx.x;
  if (e >= Etot) return;
  int dn = (e < E) ? edst[e] : (e - E);
#pragma unroll
  for (int h = 0; h < H; ++h)
    alpha[(size_t)e * H + h] = exbuf[(size_t)e * H + h] / denom[dn * H + h];
}

// ---------------- aggregation (CSR, no atomics), fused bias (+ReLU for layer 1) ----------------
__global__ __launch_bounds__(384) void agg1_kernel(const float* __restrict__ h1,
                                                   const float* __restrict__ alpha,
                                                   const int* __restrict__ rowptr,
                                                   const int* __restrict__ csr_src,
                                                   const int* __restrict__ csr_eid,
                                                   const float* __restrict__ b1,
                                                   float* __restrict__ e1out) {
  int n = blockIdx.x;
  int j = threadIdx.x;           // 0..383
  int h = j >> 7;                // head
  int p0 = rowptr[n], p1 = rowptr[n + 1];
  float acc = 0.f;
  for (int p = p0; p < p1; ++p) {
    int sn = csr_src[p];
    float a = alpha[(size_t)csr_eid[p] * 3 + h];
    acc = fmaf(a, h1[(size_t)sn * 384 + j], acc);
  }
  float v = acc + b1[j];
  e1out[(size_t)n * 384 + j] = v > 0.f ? v : 0.f;
}

__global__ __launch_bounds__(128) void agg2_kernel(const float* __restrict__ h2,
                                                   const float* __restrict__ alpha,
                                                   const int* __restrict__ rowptr,
                                                   const int* __restrict__ csr_src,
                                                   const int* __restrict__ csr_eid,
                                                   const float* __restrict__ b2,
                                                   float* __restrict__ e2out) {
  int n = blockIdx.x;
  int c = threadIdx.x;           // 0..127
  int p0 = rowptr[n], p1 = rowptr[n + 1];
  float acc = 0.f;
  for (int p = p0; p < p1; ++p) {
    int sn = csr_src[p];
    float a = alpha[csr_eid[p]];
    acc = fmaf(a, h2[(size_t)sn * 128 + c], acc);
  }
  e2out[(size_t)n * 128 + c] = acc + b2[c];
}

// ---------------- pooling ----------------
__global__ void node_attn_kernel(const float* __restrict__ alpha1, const int* __restrict__ edst,
                                 int E, int Etot, float* __restrict__ natt) {
  int e = blockIdx.x * blockDim.x + threadIdx.x;
  if (e >= Etot) return;
  int dn = (e < E) ? edst[e] : (e - E);
  float a = (alpha1[(size_t)e * 3] + alpha1[(size_t)e * 3 + 1] + alpha1[(size_t)e * 3 + 2]) * (1.f / 3.f);
  atomicAdd(&natt[dn], a);
}

__global__ __launch_bounds__(256) void pool_kernel(const float* __restrict__ e2,
                                                   const float* __restrict__ natt,
                                                   float* __restrict__ g, int N) {
  int c = blockIdx.x;            // 0..127
  int t = threadIdx.x;           // 256
  float sw = 0.f, se = 0.f;
  for (int n = t; n < N; n += 256) {
    float v = e2[(size_t)n * 128 + c];
    sw = fmaf(v, natt[n], sw);
    se += v;
  }
  __shared__ float bw[256], be[256];
  bw[t] = sw; be[t] = se;
  __syncthreads();
  for (int ofs = 128; ofs; ofs >>= 1) {
    if (t < ofs) { bw[t] += bw[t + ofs]; be[t] += be[t + ofs]; }
    __syncthreads();
  }
  if (t == 0) {
    g[c] = bw[0] / (float)N;
    g[128 + c] = be[0] / (float)N;
  }
}

__global__ __launch_bounds__(256) void sim_kernel(const float* __restrict__ g1,
                                                  const float* __restrict__ g2,
                                                  float* __restrict__ out) {
  int t = threadIdx.x;
  float a = g1[t], b = g2[t];
  __shared__ float sd[256], s1[256], s2[256];
  sd[t] = a * b; s1[t] = a * a; s2[t] = b * b;
  __syncthreads();
  for (int ofs = 128; ofs; ofs >>= 1) {
    if (t < ofs) { sd[t] += sd[t + ofs]; s1[t] += s1[t + ofs]; s2[t] += s2[t + ofs]; }
    __syncthreads();
  }
  if (t == 0) {
    float n1 = fmaxf(sqrtf(s1[0]), 1e-8f);
    float n2 = fmaxf(sqrtf(s2[0]), 1e-8f);
    out[0] = sd[0] / (n1 * n2);
  }
}

// ---------------- host ----------------
extern "C" void kernel_launch(void* const* d_in, const int* in_sizes, int n_in,
                              void* d_out, int out_size, void* d_ws, size_t ws_size,
                              hipStream_t stream) {
  const int N = in_sizes[0] / INDIM;
  const int E = in_sizes[1] / 2;
  const int Etot = E + N;

  const float* W1  = (const float*)d_in[4];
  const float* as1 = (const float*)d_in[5];
  const float* ad1 = (const float*)d_in[6];
  const float* b1  = (const float*)d_in[7];
  const float* W2  = (const float*)d_in[8];
  const float* as2 = (const float*)d_in[9];
  const float* ad2 = (const float*)d_in[10];
  const float* b2  = (const float*)d_in[11];
  float* out = (float*)d_out;

  char* p = (char*)d_ws;
  auto alloc = [&](size_t bytes) -> char* {
    char* q = p;
    p += (bytes + 255) & ~(size_t)255;
    return q;
  };
  float* h1   = (float*)alloc((size_t)N * 384 * 4);
  float* e1   = (float*)alloc((size_t)N * 384 * 4);
  float* h2   = (float*)alloc((size_t)N * 128 * 4);
  float* e2   = (float*)alloc((size_t)N * 128 * 4);
  float* s1   = (float*)alloc((size_t)N * 3 * 4);
  float* d1   = (float*)alloc((size_t)N * 3 * 4);
  float* s2   = (float*)alloc((size_t)N * 4);
  float* d2v  = (float*)alloc((size_t)N * 4);
  float* ex1  = (float*)alloc((size_t)Etot * 3 * 4);
  float* ex2  = (float*)alloc((size_t)Etot * 4);
  float* den1 = (float*)alloc((size_t)N * 3 * 4);
  float* den2 = (float*)alloc((size_t)N * 4);
  float* al2  = (float*)alloc((size_t)Etot * 4);
  float* natt = (float*)alloc((size_t)N * 4);
  float* g    = (float*)alloc(512 * 4);
  int* deg     = (int*)alloc((size_t)N * 4);
  int* rowptr  = (int*)alloc((size_t)(N + 1) * 4);
  int* cursor  = (int*)alloc((size_t)N * 4);
  int* csr_src = (int*)alloc((size_t)Etot * 4);
  int* csr_eid = (int*)alloc((size_t)Etot * 4);

  const int EB = 256;
  const int egrid = (Etot + EB - 1) / EB;
  const int gm1 = (N + 15) / 16;

  for (int b = 0; b < 2; ++b) {
    const float* x = (const float*)d_in[b ? 2 : 0];
    const int* ei = (const int*)d_in[b ? 3 : 1];
    const int* esrc = ei;
    const int* edst = ei + E;
    float* alpha1 = out + 1 + (size_t)b * (size_t)Etot * 3;

    hipMemsetAsync(deg, 0, (size_t)N * 4, stream);
    hipMemsetAsync(den1, 0, (size_t)N * 3 * 4, stream);
    hipMemsetAsync(den2, 0, (size_t)N * 4, stream);
    hipMemsetAsync(natt, 0, (size_t)N * 4, stream);

    gemm_rows<INDIM, 384, 16><<<gm1, 384, 0, stream>>>(x, W1, h1, N);
    sd_kernel<<<N * 3, 64, 0, stream>>>(h1, as1, ad1, s1, d1, 3);

    deg_kernel<<<egrid, EB, 0, stream>>>(edst, E, Etot, deg);
    scan_kernel<<<1, 1024, 0, stream>>>(deg, rowptr, cursor, N);
    fill_kernel<<<egrid, EB, 0, stream>>>(esrc, edst, E, Etot, cursor, csr_src, csr_eid);

    edge_exp_kernel<3><<<egrid, EB, 0, stream>>>(s1, d1, esrc, edst, E, Etot, ex1, den1);
    alpha_kernel<3><<<egrid, EB, 0, stream>>>(ex1, den1, edst, E, Etot, alpha1);
    agg1_kernel<<<N, 384, 0, stream>>>(h1, alpha1, rowptr, csr_src, csr_eid, b1, e1);

    gemm_rows<384, 128, 16><<<gm1, 128, 0, stream>>>(e1, W2, h2, N);
    sd_kernel<<<N, 64, 0, stream>>>(h2, as2, ad2, s2, d2v, 1);
    edge_exp_kernel<1><<<egrid, EB, 0, stream>>>(s2, d2v, esrc, edst, E, Etot, ex2, den2);
    alpha_kernel<1><<<egrid, EB, 0, stream>>>(ex2, den2, edst, E, Etot, al2);
    agg2_kernel<<<N, 128, 0, stream>>>(h2, al2, rowptr, csr_src, csr_eid, b2, e2);

    node_attn_kernel<<<egrid, EB, 0, stream>>>(alpha1, edst, E, Etot, natt);
    pool_kernel<<<128, 256, 0, stream>>>(e2, natt, g + b * 256, N);
  }
  sim_kernel<<<1, 256, 0, stream>>>(g, g + 256, out);
}

// Round 2
// 857.982 us; speedup vs baseline: 1.2238x; 1.2238x over previous
//
#include <hip/hip_runtime.h>
#include <hip/hip_bf16.h>
#include <cstdint>
#include <cstddef>

#define INDIM 256
#define NEG 0.2f

// ---------------- GEMM: Y[M,NC] = X[M,K] @ W[K,NC]; writes f32 + bf16 copies ----------------
template<int K, int NC, int BM>
__global__ __launch_bounds__(NC) void gemm_rows(const float* __restrict__ X,
                                                const float* __restrict__ W,
                                                float* __restrict__ Y,
                                                __hip_bfloat16* __restrict__ Yb,
                                                int M) {
  __shared__ float xs[BM][K];
  const int tid = threadIdx.x;
  const int row0 = blockIdx.x * BM;
  constexpr int KV = K / 4;
  for (int i = tid; i < BM * KV; i += NC) {
    int r = i / KV, c = i - r * KV;
    int gr = row0 + r;
    float4 v = make_float4(0.f, 0.f, 0.f, 0.f);
    if (gr < M) v = reinterpret_cast<const float4*>(X + (size_t)gr * K)[c];
    xs[r][c * 4 + 0] = v.x; xs[r][c * 4 + 1] = v.y;
    xs[r][c * 4 + 2] = v.z; xs[r][c * 4 + 3] = v.w;
  }
  __syncthreads();
  float acc[BM];
#pragma unroll
  for (int r = 0; r < BM; ++r) acc[r] = 0.f;
  const int j = tid;
#pragma unroll 4
  for (int k = 0; k < K; ++k) {
    float w = W[(size_t)k * NC + j];
#pragma unroll
    for (int r = 0; r < BM; ++r) acc[r] = fmaf(xs[r][k], w, acc[r]);
  }
#pragma unroll
  for (int r = 0; r < BM; ++r) {
    int gr = row0 + r;
    if (gr < M) {
      Y[(size_t)gr * NC + j] = acc[r];
      Yb[(size_t)gr * NC + j] = __float2bfloat16(acc[r]);
    }
  }
}

// ---------------- attention dots: one wave per (node,head) ----------------
__global__ __launch_bounds__(256) void sd_kernel(const float* __restrict__ H,
                                                 const float* __restrict__ As,
                                                 const float* __restrict__ Ad,
                                                 float* __restrict__ S, float* __restrict__ D,
                                                 int NB, int NH) {
  int w = blockIdx.x * 4 + (threadIdx.x >> 6);
  if (w >= NB) return;
  int lane = threadIdx.x & 63;
  int h = w % NH;
  float2 hv = reinterpret_cast<const float2*>(H + (size_t)w * 128)[lane];
  float2 as = reinterpret_cast<const float2*>(As + h * 128)[lane];
  float2 ad = reinterpret_cast<const float2*>(Ad + h * 128)[lane];
  float vs = hv.x * as.x + hv.y * as.y;
  float vd = hv.x * ad.x + hv.y * ad.y;
#pragma unroll
  for (int o = 32; o; o >>= 1) { vs += __shfl_down(vs, o); vd += __shfl_down(vd, o); }
  if (lane == 0) { S[w] = vs; D[w] = vd; }
}

// ---------------- CSR build ----------------
__global__ void deg_kernel(const int* __restrict__ edst, int E, int Etot, int* __restrict__ deg) {
  int e = blockIdx.x * blockDim.x + threadIdx.x;
  if (e >= Etot) return;
  int dn = (e < E) ? edst[e] : (e - E);
  atomicAdd(&deg[dn], 1);
}

__global__ __launch_bounds__(1024) void scan_kernel(const int* __restrict__ deg,
                                                    int* __restrict__ rowptr,
                                                    int* __restrict__ cursor, int n) {
  __shared__ int wsum[16];
  __shared__ int carry_s;
  int tid = threadIdx.x;
  int lane = tid & 63, wid = tid >> 6;
  if (tid == 0) { carry_s = 0; rowptr[0] = 0; }
  __syncthreads();
  for (int base = 0; base < n; base += 1024) {
    int i = base + tid;
    int v = (i < n) ? deg[i] : 0;
    int x = v;
#pragma unroll
    for (int o = 1; o < 64; o <<= 1) {
      int t = __shfl_up(x, o);
      if (lane >= o) x += t;
    }
    if (lane == 63) wsum[wid] = x;
    __syncthreads();
    if (wid == 0) {
      int wv = (lane < 16) ? wsum[lane] : 0;
#pragma unroll
      for (int o = 1; o < 16; o <<= 1) {
        int t = __shfl_up(wv, o);
        if (lane >= o) wv += t;
      }
      if (lane < 16) wsum[lane] = wv;
    }
    __syncthreads();
    int incl = carry_s + (wid ? wsum[wid - 1] : 0) + x;
    if (i < n) { rowptr[i + 1] = incl; cursor[i] = incl - v; }
    __syncthreads();
    if (tid == 1023) carry_s = incl;
    __syncthreads();
  }
}

__global__ void fill_kernel(const int* __restrict__ esrc, const int* __restrict__ edst,
                            int E, int Etot, int* __restrict__ cursor,
                            int* __restrict__ csr_src, int* __restrict__ csr_eid) {
  int e = blockIdx.x * blockDim.x + threadIdx.x;
  if (e >= Etot) return;
  int s, dn;
  if (e < E) { s = esrc[e]; dn = edst[e]; } else { s = dn = e - E; }
  int pos = atomicAdd(&cursor[dn], 1);
  csr_src[pos] = s;
  csr_eid[pos] = e;
}

// ---------------- edge softmax denom (no max-shift: identical math, fp32-safe) ----------------
template<int H>
__global__ void edge_den_kernel(const float* __restrict__ S, const float* __restrict__ D,
                                const int* __restrict__ esrc, const int* __restrict__ edst,
                                int E, int Etot, float* __restrict__ denom) {
  int e = blockIdx.x * blockDim.x + threadIdx.x;
  if (e >= Etot) return;
  int sn, dn;
  if (e < E) { sn = esrc[e]; dn = edst[e]; } else { sn = dn = e - E; }
#pragma unroll
  for (int h = 0; h < H; ++h) {
    float v = S[sn * H + h] + D[dn * H + h];
    v = (v > 0.f) ? v : NEG * v;
    atomicAdd(&denom[dn * H + h], expf(v));
  }
}

__global__ void alpha3_kernel(const float* __restrict__ S, const float* __restrict__ D,
                              const int* __restrict__ esrc, const int* __restrict__ edst,
                              int E, int Etot, const float* __restrict__ denom,
                              float* __restrict__ alpha) {
  int e = blockIdx.x * blockDim.x + threadIdx.x;
  if (e >= Etot) return;
  int sn, dn;
  if (e < E) { sn = esrc[e]; dn = edst[e]; } else { sn = dn = e - E; }
#pragma unroll
  for (int h = 0; h < 3; ++h) {
    float v = S[sn * 3 + h] + D[dn * 3 + h];
    v = (v > 0.f) ? v : NEG * v;
    alpha[(size_t)e * 3 + h] = expf(v) / denom[dn * 3 + h];
  }
}

// ---------------- aggregation layer 1: 192 threads, bf16x2 per thread, LDS-staged metadata ----
__global__ __launch_bounds__(192) void agg1_kernel(const __hip_bfloat16* __restrict__ h1b,
                                                   const float* __restrict__ alpha,
                                                   const int* __restrict__ rowptr,
                                                   const int* __restrict__ csr_src,
                                                   const int* __restrict__ csr_eid,
                                                   const float* __restrict__ b1,
                                                   float* __restrict__ e1out) {
  __shared__ int lsrc[128];
  __shared__ float la[3][128];
  int n = blockIdx.x;
  int j = threadIdx.x;           // 0..191 -> cols 2j, 2j+1
  int head = j >> 6;             // wave id == head
  int p0 = rowptr[n], p1 = rowptr[n + 1];
  float acc0 = 0.f, acc1 = 0.f;
  for (int base = p0; base < p1; base += 128) {
    int cnt = min(128, p1 - base);
    __syncthreads();
    if (j < cnt) {
      lsrc[j] = csr_src[base + j];
      size_t eid = (size_t)csr_eid[base + j];
      la[0][j] = alpha[eid * 3];
      la[1][j] = alpha[eid * 3 + 1];
      la[2][j] = alpha[eid * 3 + 2];
    }
    __syncthreads();
    for (int i = 0; i < cnt; ++i) {
      int sn = lsrc[i];
      float a = la[head][i];
      __hip_bfloat162 hv = reinterpret_cast<const __hip_bfloat162*>(h1b)[(size_t)sn * 192 + j];
      acc0 = fmaf(a, __bfloat162float(hv.x), acc0);
      acc1 = fmaf(a, __bfloat162float(hv.y), acc1);
    }
  }
  int c0 = 2 * j;
  float v0 = acc0 + b1[c0];
  float v1 = acc1 + b1[c0 + 1];
  e1out[(size_t)n * 384 + c0]     = v0 > 0.f ? v0 : 0.f;
  e1out[(size_t)n * 384 + c0 + 1] = v1 > 0.f ? v1 : 0.f;
}

// ---------------- aggregation layer 2: inline alpha, 64 threads, bf16x2 per thread ----------
__global__ __launch_bounds__(64) void agg2_kernel(const __hip_bfloat16* __restrict__ h2b,
                                                  const float* __restrict__ S,
                                                  const float* __restrict__ D,
                                                  const float* __restrict__ den,
                                                  const int* __restrict__ rowptr,
                                                  const int* __restrict__ csr_src,
                                                  const float* __restrict__ b2,
                                                  float* __restrict__ e2out) {
  __shared__ int lsrc[128];
  __shared__ float la[128];
  int n = blockIdx.x;
  int c = threadIdx.x;           // 0..63 -> cols 2c, 2c+1
  int p0 = rowptr[n], p1 = rowptr[n + 1];
  float dn_v = D[n];
  float invden = 1.f / den[n];
  float acc0 = 0.f, acc1 = 0.f;
  for (int base = p0; base < p1; base += 128) {
    int cnt = min(128, p1 - base);
    __syncthreads();
    for (int i = c; i < cnt; i += 64) {
      int sn = csr_src[base + i];
      float v = S[sn] + dn_v;
      v = (v > 0.f) ? v : NEG * v;
      lsrc[i] = sn;
      la[i] = expf(v) * invden;
    }
    __syncthreads();
    for (int i = 0; i < cnt; ++i) {
      int sn = lsrc[i];
      float a = la[i];
      __hip_bfloat162 hv = reinterpret_cast<const __hip_bfloat162*>(h2b)[(size_t)sn * 64 + c];
      acc0 = fmaf(a, __bfloat162float(hv.x), acc0);
      acc1 = fmaf(a, __bfloat162float(hv.y), acc1);
    }
  }
  int c0 = 2 * c;
  e2out[(size_t)n * 128 + c0]     = acc0 + b2[c0];
  e2out[(size_t)n * 128 + c0 + 1] = acc1 + b2[c0 + 1];
}

// ---------------- pooling: node_attn == 1 exactly (softmax sums), so both halves = mean ------
__global__ __launch_bounds__(128) void pool_kernel(const float* __restrict__ e2,
                                                   float* __restrict__ g, int N, float invN) {
  int c = threadIdx.x;
  int r0 = blockIdx.x * 128;
  int r1 = min(r0 + 128, N);
  float acc = 0.f;
  for (int n = r0; n < r1; ++n) acc += e2[(size_t)n * 128 + c];
  acc *= invN;
  atomicAdd(&g[c], acc);
  atomicAdd(&g[128 + c], acc);
}

__global__ __launch_bounds__(256) void sim_kernel(const float* __restrict__ g1,
                                                  const float* __restrict__ g2,
                                                  float* __restrict__ out) {
  int t = threadIdx.x;
  float a = g1[t], b = g2[t];
  __shared__ float sd[256], s1[256], s2[256];
  sd[t] = a * b; s1[t] = a * a; s2[t] = b * b;
  __syncthreads();
  for (int ofs = 128; ofs; ofs >>= 1) {
    if (t < ofs) { sd[t] += sd[t + ofs]; s1[t] += s1[t + ofs]; s2[t] += s2[t + ofs]; }
    __syncthreads();
  }
  if (t == 0) {
    float n1 = fmaxf(sqrtf(s1[0]), 1e-8f);
    float n2 = fmaxf(sqrtf(s2[0]), 1e-8f);
    out[0] = sd[0] / (n1 * n2);
  }
}

// ---------------- host ----------------
extern "C" void kernel_launch(void* const* d_in, const int* in_sizes, int n_in,
                              void* d_out, int out_size, void* d_ws, size_t ws_size,
                              hipStream_t stream) {
  const int N = in_sizes[0] / INDIM;
  const int E = in_sizes[1] / 2;
  const int Etot = E + N;

  const float* W1  = (const float*)d_in[4];
  const float* as1 = (const float*)d_in[5];
  const float* ad1 = (const float*)d_in[6];
  const float* b1  = (const float*)d_in[7];
  const float* W2  = (const float*)d_in[8];
  const float* as2 = (const float*)d_in[9];
  const float* ad2 = (const float*)d_in[10];
  const float* b2  = (const float*)d_in[11];
  float* out = (float*)d_out;

  char* p = (char*)d_ws;
  auto alloc = [&](size_t bytes) -> char* {
    char* q = p;
    p += (bytes + 255) & ~(size_t)255;
    return q;
  };
  // region A: h1 (f32, N*384); e2 (N*128) aliases it (h1 dead before agg2 writes e2)
  float* h1 = (float*)alloc((size_t)N * 384 * 4);
  float* e2 = h1;
  // region B: h1b (bf16 N*384); h2 (f32 N*128) + h2b (bf16 N*128) alias it (h1b dead before gemm2)
  char* regB = alloc((size_t)N * 384 * 2);
  __hip_bfloat16* h1b = (__hip_bfloat16*)regB;
  float* h2           = (float*)regB;
  __hip_bfloat16* h2b = (__hip_bfloat16*)(regB + (size_t)N * 128 * 4);
  float* e1 = (float*)alloc((size_t)N * 384 * 4);
  float* s1   = (float*)alloc((size_t)N * 3 * 4);
  float* d1   = (float*)alloc((size_t)N * 3 * 4);
  float* s2   = (float*)alloc((size_t)N * 4);
  float* d2v  = (float*)alloc((size_t)N * 4);
  float* den1 = (float*)alloc((size_t)N * 3 * 4);
  float* den2 = (float*)alloc((size_t)N * 4);
  float* g    = (float*)alloc(512 * 4);
  int* deg     = (int*)alloc((size_t)N * 4);
  int* rowptr  = (int*)alloc((size_t)(N + 1) * 4);
  int* cursor  = (int*)alloc((size_t)N * 4);
  int* csr_src = (int*)alloc((size_t)Etot * 4);
  int* csr_eid = (int*)alloc((size_t)Etot * 4);

  const int EB = 256;
  const int egrid = (Etot + EB - 1) / EB;
  const int gm = (N + 31) / 32;

  hipMemsetAsync(g, 0, 512 * 4, stream);

  for (int b = 0; b < 2; ++b) {
    const float* x = (const float*)d_in[b ? 2 : 0];
    const int* ei = (const int*)d_in[b ? 3 : 1];
    const int* esrc = ei;
    const int* edst = ei + E;
    float* alpha1 = out + 1 + (size_t)b * (size_t)Etot * 3;

    hipMemsetAsync(deg, 0, (size_t)N * 4, stream);
    hipMemsetAsync(den1, 0, (size_t)N * 3 * 4, stream);
    hipMemsetAsync(den2, 0, (size_t)N * 4, stream);

    gemm_rows<INDIM, 384, 32><<<gm, 384, 0, stream>>>(x, W1, h1, h1b, N);
    sd_kernel<<<(N * 3 + 3) / 4, 256, 0, stream>>>(h1, as1, ad1, s1, d1, N * 3, 3);

    deg_kernel<<<egrid, EB, 0, stream>>>(edst, E, Etot, deg);
    scan_kernel<<<1, 1024, 0, stream>>>(deg, rowptr, cursor, N);
    fill_kernel<<<egrid, EB, 0, stream>>>(esrc, edst, E, Etot, cursor, csr_src, csr_eid);

    edge_den_kernel<3><<<egrid, EB, 0, stream>>>(s1, d1, esrc, edst, E, Etot, den1);
    alpha3_kernel<<<egrid, EB, 0, stream>>>(s1, d1, esrc, edst, E, Etot, den1, alpha1);
    agg1_kernel<<<N, 192, 0, stream>>>(h1b, alpha1, rowptr, csr_src, csr_eid, b1, e1);

    gemm_rows<384, 128, 32><<<gm, 128, 0, stream>>>(e1, W2, h2, h2b, N);
    sd_kernel<<<(N + 3) / 4, 256, 0, stream>>>(h2, as2, ad2, s2, d2v, N, 1);
    edge_den_kernel<1><<<egrid, EB, 0, stream>>>(s2, d2v, esrc, edst, E, Etot, den2);
    agg2_kernel<<<N, 64, 0, stream>>>(h2b, s2, d2v, den2, rowptr, csr_src, b2, e2);

    pool_kernel<<<(N + 127) / 128, 128, 0, stream>>>(e2, g + b * 256, N, 1.f / (float)N);
  }
  sim_kernel<<<1, 256, 0, stream>>>(g, g + 256, out);
}

// Round 3
// 567.880 us; speedup vs baseline: 1.8490x; 1.5109x over previous
//
#include <hip/hip_runtime.h>
#include <hip/hip_bf16.h>
#include <cstdint>
#include <cstddef>

#define INDIM 256
#define NEG 0.2f

typedef __attribute__((ext_vector_type(8))) short short8v;
typedef __attribute__((ext_vector_type(4))) float f32x4;

__device__ __forceinline__ unsigned short f2bf(float x) {
  __hip_bfloat16 b = __float2bfloat16(x);
  return __builtin_bit_cast(unsigned short, b);
}

// ---------------- W pre-transpose to bf16: Wt[c][k] = bf16(W[k][c]) ----------------
__global__ void wprep_kernel(const float* __restrict__ W, __hip_bfloat16* __restrict__ Wt,
                             int K, int NC, int total) {
  int idx = blockIdx.x * blockDim.x + threadIdx.x;
  if (idx >= total) return;
  int k = idx / NC, c = idx - k * NC;
  Wt[(size_t)c * K + k] = __float2bfloat16(W[idx]);
}

// ---------------- MFMA GEMM: Y[M,NC] = A[M,K] @ W[K,NC]; Wt is [NC][K] bf16 -------------
// tile 64x128, 4 waves (2x2), wave tile 32x64 = 2x4 fragments of 16x16, BK=32
template<int K, bool ABF16>
__global__ __launch_bounds__(256) void mfma_gemm(const void* __restrict__ Ain,
                                                 const __hip_bfloat16* __restrict__ Wt,
                                                 float* __restrict__ Y,
                                                 __hip_bfloat16* __restrict__ Yb,
                                                 int M, int NC) {
  __shared__ short As[64][40];
  __shared__ short Bs[128][40];
  const int tid = threadIdx.x;
  const int row0 = blockIdx.x * 64;
  const int col0 = blockIdx.y * 128;
  const int l = tid & 63, w = tid >> 6;
  const int wr = w >> 1, wc = w & 1;
  const int lr = l & 15, lk = (l >> 4) * 8;

  f32x4 acc[2][4];
#pragma unroll
  for (int m = 0; m < 2; ++m)
#pragma unroll
    for (int n = 0; n < 4; ++n) acc[m][n] = {0.f, 0.f, 0.f, 0.f};

  for (int k0 = 0; k0 < K; k0 += 32) {
    __syncthreads();
    {  // stage A: 64 rows x 32 k
      int r = tid >> 2, kq = (tid & 3) * 8;
      int gr = row0 + r;
      short8v av = {0, 0, 0, 0, 0, 0, 0, 0};
      if (gr < M) {
        if (ABF16) {
          av = *(const short8v*)((const short*)Ain + (size_t)gr * K + k0 + kq);
        } else {
          const float* ap = (const float*)Ain + (size_t)gr * K + k0 + kq;
          float4 u = *(const float4*)ap;
          float4 v = *(const float4*)(ap + 4);
          av = short8v{(short)f2bf(u.x), (short)f2bf(u.y), (short)f2bf(u.z), (short)f2bf(u.w),
                       (short)f2bf(v.x), (short)f2bf(v.y), (short)f2bf(v.z), (short)f2bf(v.w)};
        }
      }
      *(short8v*)&As[r][kq] = av;
    }
    {  // stage B: 128 cols x 32 k (Wt row-major [NC][K])
      int c = tid >> 1, kq = (tid & 1) * 8;
      const short* wp = (const short*)Wt + (size_t)(col0 + c) * K + k0 + kq;
      *(short8v*)&Bs[c][kq]      = *(const short8v*)wp;
      *(short8v*)&Bs[c][kq + 16] = *(const short8v*)(wp + 16);
    }
    __syncthreads();
    short8v a[2], b[4];
#pragma unroll
    for (int m = 0; m < 2; ++m) a[m] = *(short8v*)&As[wr * 32 + m * 16 + lr][lk];
#pragma unroll
    for (int n = 0; n < 4; ++n) b[n] = *(short8v*)&Bs[wc * 64 + n * 16 + lr][lk];
#pragma unroll
    for (int m = 0; m < 2; ++m)
#pragma unroll
      for (int n = 0; n < 4; ++n)
        acc[m][n] = __builtin_amdgcn_mfma_f32_16x16x32_bf16(a[m], b[n], acc[m][n], 0, 0, 0);
  }
  // epilogue: C/D layout col=lane&15, row=(lane>>4)*4+q
#pragma unroll
  for (int m = 0; m < 2; ++m) {
    int rbase = row0 + wr * 32 + m * 16 + (l >> 4) * 4;
#pragma unroll
    for (int n = 0; n < 4; ++n) {
      int col = col0 + wc * 64 + n * 16 + lr;
#pragma unroll
      for (int q = 0; q < 4; ++q) {
        int row = rbase + q;
        if (row < M) {
          float v = acc[m][n][q];
          Y[(size_t)row * NC + col] = v;
          Yb[(size_t)row * NC + col] = __float2bfloat16(v);
        }
      }
    }
  }
}

// ---------------- attention dots: one wave per (node,head) ----------------
__global__ __launch_bounds__(256) void sd_kernel(const float* __restrict__ H,
                                                 const float* __restrict__ As,
                                                 const float* __restrict__ Ad,
                                                 float* __restrict__ S, float* __restrict__ D,
                                                 int NB, int NH) {
  int w = blockIdx.x * 4 + (threadIdx.x >> 6);
  if (w >= NB) return;
  int lane = threadIdx.x & 63;
  int h = w % NH;
  float2 hv = reinterpret_cast<const float2*>(H + (size_t)w * 128)[lane];
  float2 as = reinterpret_cast<const float2*>(As + h * 128)[lane];
  float2 ad = reinterpret_cast<const float2*>(Ad + h * 128)[lane];
  float vs = hv.x * as.x + hv.y * as.y;
  float vd = hv.x * ad.x + hv.y * ad.y;
#pragma unroll
  for (int o = 32; o; o >>= 1) { vs += __shfl_down(vs, o); vd += __shfl_down(vd, o); }
  if (lane == 0) { S[w] = vs; D[w] = vd; }
}

// ---------------- CSR build ----------------
__global__ void deg_kernel(const int* __restrict__ edst, int E, int Etot, int* __restrict__ deg) {
  int e = blockIdx.x * blockDim.x + threadIdx.x;
  if (e >= Etot) return;
  int dn = (e < E) ? edst[e] : (e - E);
  atomicAdd(&deg[dn], 1);
}

__global__ __launch_bounds__(1024) void scan_kernel(const int* __restrict__ deg,
                                                    int* __restrict__ rowptr,
                                                    int* __restrict__ cursor, int n) {
  __shared__ int wsum[16];
  __shared__ int carry_s;
  int tid = threadIdx.x;
  int lane = tid & 63, wid = tid >> 6;
  if (tid == 0) { carry_s = 0; rowptr[0] = 0; }
  __syncthreads();
  for (int base = 0; base < n; base += 1024) {
    int i = base + tid;
    int v = (i < n) ? deg[i] : 0;
    int x = v;
#pragma unroll
    for (int o = 1; o < 64; o <<= 1) {
      int t = __shfl_up(x, o);
      if (lane >= o) x += t;
    }
    if (lane == 63) wsum[wid] = x;
    __syncthreads();
    if (wid == 0) {
      int wv = (lane < 16) ? wsum[lane] : 0;
#pragma unroll
      for (int o = 1; o < 16; o <<= 1) {
        int t = __shfl_up(wv, o);
        if (lane >= o) wv += t;
      }
      if (lane < 16) wsum[lane] = wv;
    }
    __syncthreads();
    int incl = carry_s + (wid ? wsum[wid - 1] : 0) + x;
    if (i < n) { rowptr[i + 1] = incl; cursor[i] = incl - v; }
    __syncthreads();
    if (tid == 1023) carry_s = incl;
    __syncthreads();
  }
}

__global__ void fill_kernel(const int* __restrict__ esrc, const int* __restrict__ edst,
                            int E, int Etot, int* __restrict__ cursor,
                            int* __restrict__ csr_src, int* __restrict__ csr_eid) {
  int e = blockIdx.x * blockDim.x + threadIdx.x;
  if (e >= Etot) return;
  int s, dn;
  if (e < E) { s = esrc[e]; dn = edst[e]; } else { s = dn = e - E; }
  int pos = atomicAdd(&cursor[dn], 1);
  csr_src[pos] = s;
  csr_eid[pos] = e;
}

// ---------------- edge softmax denom (no max-shift: identical math, fp32-safe) ----------------
template<int H>
__global__ void edge_den_kernel(const float* __restrict__ S, const float* __restrict__ D,
                                const int* __restrict__ esrc, const int* __restrict__ edst,
                                int E, int Etot, float* __restrict__ denom) {
  int e = blockIdx.x * blockDim.x + threadIdx.x;
  if (e >= Etot) return;
  int sn, dn;
  if (e < E) { sn = esrc[e]; dn = edst[e]; } else { sn = dn = e - E; }
#pragma unroll
  for (int h = 0; h < H; ++h) {
    float v = S[sn * H + h] + D[dn * H + h];
    v = (v > 0.f) ? v : NEG * v;
    atomicAdd(&denom[dn * H + h], expf(v));
  }
}

__global__ void alpha3_kernel(const float* __restrict__ S, const float* __restrict__ D,
                              const int* __restrict__ esrc, const int* __restrict__ edst,
                              int E, int Etot, const float* __restrict__ denom,
                              float* __restrict__ alpha) {
  int e = blockIdx.x * blockDim.x + threadIdx.x;
  if (e >= Etot) return;
  int sn, dn;
  if (e < E) { sn = esrc[e]; dn = edst[e]; } else { sn = dn = e - E; }
#pragma unroll
  for (int h = 0; h < 3; ++h) {
    float v = S[sn * 3 + h] + D[dn * 3 + h];
    v = (v > 0.f) ? v : NEG * v;
    alpha[(size_t)e * 3 + h] = expf(v) / denom[dn * 3 + h];
  }
}

// ---------------- aggregation layer 1: 192 threads, bf16x2 per thread, LDS-staged metadata ----
__global__ __launch_bounds__(192) void agg1_kernel(const __hip_bfloat16* __restrict__ h1b,
                                                   const float* __restrict__ alpha,
                                                   const int* __restrict__ rowptr,
                                                   const int* __restrict__ csr_src,
                                                   const int* __restrict__ csr_eid,
                                                   const float* __restrict__ b1,
                                                   __hip_bfloat16* __restrict__ e1b) {
  __shared__ int lsrc[128];
  __shared__ float la[3][128];
  int n = blockIdx.x;
  int j = threadIdx.x;           // 0..191 -> cols 2j, 2j+1
  int head = j >> 6;             // wave id == head
  int p0 = rowptr[n], p1 = rowptr[n + 1];
  float acc0 = 0.f, acc1 = 0.f;
  for (int base = p0; base < p1; base += 128) {
    int cnt = min(128, p1 - base);
    __syncthreads();
    if (j < cnt) {
      lsrc[j] = csr_src[base + j];
      size_t eid = (size_t)csr_eid[base + j];
      la[0][j] = alpha[eid * 3];
      la[1][j] = alpha[eid * 3 + 1];
      la[2][j] = alpha[eid * 3 + 2];
    }
    __syncthreads();
    for (int i = 0; i < cnt; ++i) {
      int sn = lsrc[i];
      float a = la[head][i];
      __hip_bfloat162 hv = reinterpret_cast<const __hip_bfloat162*>(h1b)[(size_t)sn * 192 + j];
      acc0 = fmaf(a, __bfloat162float(hv.x), acc0);
      acc1 = fmaf(a, __bfloat162float(hv.y), acc1);
    }
  }
  int c0 = 2 * j;
  float v0 = acc0 + b1[c0];
  float v1 = acc1 + b1[c0 + 1];
  __hip_bfloat162 ov;
  ov.x = __float2bfloat16(v0 > 0.f ? v0 : 0.f);
  ov.y = __float2bfloat16(v1 > 0.f ? v1 : 0.f);
  reinterpret_cast<__hip_bfloat162*>(e1b)[(size_t)n * 192 + j] = ov;
}

// ---------------- aggregation layer 2: inline alpha, 64 threads, bf16x2 per thread ----------
__global__ __launch_bounds__(64) void agg2_kernel(const __hip_bfloat16* __restrict__ h2b,
                                                  const float* __restrict__ S,
                                                  const float* __restrict__ D,
                                                  const float* __restrict__ den,
                                                  const int* __restrict__ rowptr,
                                                  const int* __restrict__ csr_src,
                                                  const float* __restrict__ b2,
                                                  float* __restrict__ e2out) {
  __shared__ int lsrc[128];
  __shared__ float la[128];
  int n = blockIdx.x;
  int c = threadIdx.x;           // 0..63 -> cols 2c, 2c+1
  int p0 = rowptr[n], p1 = rowptr[n + 1];
  float dn_v = D[n];
  float invden = 1.f / den[n];
  float acc0 = 0.f, acc1 = 0.f;
  for (int base = p0; base < p1; base += 128) {
    int cnt = min(128, p1 - base);
    __syncthreads();
    for (int i = c; i < cnt; i += 64) {
      int sn = csr_src[base + i];
      float v = S[sn] + dn_v;
      v = (v > 0.f) ? v : NEG * v;
      lsrc[i] = sn;
      la[i] = expf(v) * invden;
    }
    __syncthreads();
    for (int i = 0; i < cnt; ++i) {
      int sn = lsrc[i];
      float a = la[i];
      __hip_bfloat162 hv = reinterpret_cast<const __hip_bfloat162*>(h2b)[(size_t)sn * 64 + c];
      acc0 = fmaf(a, __bfloat162float(hv.x), acc0);
      acc1 = fmaf(a, __bfloat162float(hv.y), acc1);
    }
  }
  int c0 = 2 * c;
  e2out[(size_t)n * 128 + c0]     = acc0 + b2[c0];
  e2out[(size_t)n * 128 + c0 + 1] = acc1 + b2[c0 + 1];
}

// ---------------- pooling: node_attn == 1 exactly (softmax sums), so both halves = mean ------
__global__ __launch_bounds__(128) void pool_kernel(const float* __restrict__ e2,
                                                   float* __restrict__ g, int N, float invN) {
  int c = threadIdx.x;
  int r0 = blockIdx.x * 128;
  int r1 = min(r0 + 128, N);
  float acc = 0.f;
  for (int n = r0; n < r1; ++n) acc += e2[(size_t)n * 128 + c];
  acc *= invN;
  atomicAdd(&g[c], acc);
  atomicAdd(&g[128 + c], acc);
}

__global__ __launch_bounds__(256) void sim_kernel(const float* __restrict__ g1,
                                                  const float* __restrict__ g2,
                                                  float* __restrict__ out) {
  int t = threadIdx.x;
  float a = g1[t], b = g2[t];
  __shared__ float sd[256], s1[256], s2[256];
  sd[t] = a * b; s1[t] = a * a; s2[t] = b * b;
  __syncthreads();
  for (int ofs = 128; ofs; ofs >>= 1) {
    if (t < ofs) { sd[t] += sd[t + ofs]; s1[t] += s1[t + ofs]; s2[t] += s2[t + ofs]; }
    __syncthreads();
  }
  if (t == 0) {
    float n1 = fmaxf(sqrtf(s1[0]), 1e-8f);
    float n2 = fmaxf(sqrtf(s2[0]), 1e-8f);
    out[0] = sd[0] / (n1 * n2);
  }
}

// ---------------- host ----------------
extern "C" void kernel_launch(void* const* d_in, const int* in_sizes, int n_in,
                              void* d_out, int out_size, void* d_ws, size_t ws_size,
                              hipStream_t stream) {
  const int N = in_sizes[0] / INDIM;
  const int E = in_sizes[1] / 2;
  const int Etot = E + N;

  const float* W1  = (const float*)d_in[4];
  const float* as1 = (const float*)d_in[5];
  const float* ad1 = (const float*)d_in[6];
  const float* b1  = (const float*)d_in[7];
  const float* W2  = (const float*)d_in[8];
  const float* as2 = (const float*)d_in[9];
  const float* ad2 = (const float*)d_in[10];
  const float* b2  = (const float*)d_in[11];
  float* out = (float*)d_out;

  char* p = (char*)d_ws;
  auto alloc = [&](size_t bytes) -> char* {
    char* q = p;
    p += (bytes + 255) & ~(size_t)255;
    return q;
  };
  // region A: h1 (f32, N*384); e2 (N*128) aliases it (h1 dead before agg2 writes e2)
  float* h1 = (float*)alloc((size_t)N * 384 * 4);
  float* e2 = h1;
  // region B: h1b (bf16 N*384); h2 (f32 N*128) + h2b (bf16 N*128) alias it (h1b dead before gemm2)
  char* regB = alloc((size_t)N * 384 * 2);
  __hip_bfloat16* h1b = (__hip_bfloat16*)regB;
  float* h2           = (float*)regB;
  __hip_bfloat16* h2b = (__hip_bfloat16*)(regB + (size_t)N * 128 * 4);
  __hip_bfloat16* e1b = (__hip_bfloat16*)alloc((size_t)N * 384 * 2);
  __hip_bfloat16* W1t = (__hip_bfloat16*)alloc((size_t)256 * 384 * 2);
  __hip_bfloat16* W2t = (__hip_bfloat16*)alloc((size_t)384 * 128 * 2);
  float* s1   = (float*)alloc((size_t)N * 3 * 4);
  float* d1   = (float*)alloc((size_t)N * 3 * 4);
  float* s2   = (float*)alloc((size_t)N * 4);
  float* d2v  = (float*)alloc((size_t)N * 4);
  float* den1 = (float*)alloc((size_t)N * 3 * 4);
  float* den2 = (float*)alloc((size_t)N * 4);
  float* g    = (float*)alloc(512 * 4);
  int* deg     = (int*)alloc((size_t)N * 4);
  int* rowptr  = (int*)alloc((size_t)(N + 1) * 4);
  int* cursor  = (int*)alloc((size_t)N * 4);
  int* csr_src = (int*)alloc((size_t)Etot * 4);
  int* csr_eid = (int*)alloc((size_t)Etot * 4);

  const int EB = 256;
  const int egrid = (Etot + EB - 1) / EB;
  const int gmx = (N + 63) / 64;

  hipMemsetAsync(g, 0, 512 * 4, stream);
  wprep_kernel<<<(256 * 384 + 255) / 256, 256, 0, stream>>>(W1, W1t, 256, 384, 256 * 384);
  wprep_kernel<<<(384 * 128 + 255) / 256, 256, 0, stream>>>(W2, W2t, 384, 128, 384 * 128);

  for (int b = 0; b < 2; ++b) {
    const float* x = (const float*)d_in[b ? 2 : 0];
    const int* ei = (const int*)d_in[b ? 3 : 1];
    const int* esrc = ei;
    const int* edst = ei + E;
    float* alpha1 = out + 1 + (size_t)b * (size_t)Etot * 3;

    hipMemsetAsync(deg, 0, (size_t)N * 4, stream);
    hipMemsetAsync(den1, 0, (size_t)N * 3 * 4, stream);
    hipMemsetAsync(den2, 0, (size_t)N * 4, stream);

    mfma_gemm<256, false><<<dim3(gmx, 3), 256, 0, stream>>>(x, W1t, h1, h1b, N, 384);
    sd_kernel<<<(N * 3 + 3) / 4, 256, 0, stream>>>(h1, as1, ad1, s1, d1, N * 3, 3);

    deg_kernel<<<egrid, EB, 0, stream>>>(edst, E, Etot, deg);
    scan_kernel<<<1, 1024, 0, stream>>>(deg, rowptr, cursor, N);
    fill_kernel<<<egrid, EB, 0, stream>>>(esrc, edst, E, Etot, cursor, csr_src, csr_eid);

    edge_den_kernel<3><<<egrid, EB, 0, stream>>>(s1, d1, esrc, edst, E, Etot, den1);
    alpha3_kernel<<<egrid, EB, 0, stream>>>(s1, d1, esrc, edst, E, Etot, den1, alpha1);
    agg1_kernel<<<N, 192, 0, stream>>>(h1b, alpha1, rowptr, csr_src, csr_eid, b1, e1b);

    mfma_gemm<384, true><<<dim3(gmx, 1), 256, 0, stream>>>(e1b, W2t, h2, h2b, N, 128);
    sd_kernel<<<(N + 3) / 4, 256, 0, stream>>>(h2, as2, ad2, s2, d2v, N, 1);
    edge_den_kernel<1><<<egrid, EB, 0, stream>>>(s2, d2v, esrc, edst, E, Etot, den2);
    agg2_kernel<<<N, 64, 0, stream>>>(h2b, s2, d2v, den2, rowptr, csr_src, b2, e2);

    pool_kernel<<<(N + 127) / 128, 128, 0, stream>>>(e2, g + b * 256, N, 1.f / (float)N);
  }
  sim_kernel<<<1, 256, 0, stream>>>(g, g + 256, out);
}

// Round 4
// 387.343 us; speedup vs baseline: 2.7109x; 1.4661x over previous
//
#include <hip/hip_runtime.h>
#include <hip/hip_bf16.h>
#include <cstdint>
#include <cstddef>

#define INDIM 256
#define NEG 0.2f

typedef __attribute__((ext_vector_type(8))) short short8v;
typedef __attribute__((ext_vector_type(4))) float f32x4;

__device__ __forceinline__ unsigned short f2bf(float x) {
  __hip_bfloat16 b = __float2bfloat16(x);
  return __builtin_bit_cast(unsigned short, b);
}

__device__ __forceinline__ float lrelu(float v) { return v > 0.f ? v : NEG * v; }

// ---------------- W pre-transpose to bf16: Wt[c][k] = bf16(W[k][c]) ----------------
__global__ void wprep_kernel(const float* __restrict__ W, __hip_bfloat16* __restrict__ Wt,
                             int K, int NC, int total) {
  int idx = blockIdx.x * blockDim.x + threadIdx.x;
  if (idx >= total) return;
  int k = idx / NC, c = idx - k * NC;
  Wt[(size_t)c * K + k] = __float2bfloat16(W[idx]);
}

// ---------------- MFMA GEMM: Y[M,NC] = A[M,K] @ W[K,NC]; Wt is [NC][K] bf16 -------------
// tile 64x128, 4 waves (2x2), wave tile 32x64 = 2x4 fragments of 16x16, BK=32
template<int K, bool ABF16>
__global__ __launch_bounds__(256) void mfma_gemm(const void* __restrict__ Ain,
                                                 const __hip_bfloat16* __restrict__ Wt,
                                                 float* __restrict__ Y,
                                                 __hip_bfloat16* __restrict__ Yb,
                                                 int M, int NC) {
  __shared__ short As[64][40];
  __shared__ short Bs[128][40];
  const int tid = threadIdx.x;
  const int row0 = blockIdx.x * 64;
  const int col0 = blockIdx.y * 128;
  const int l = tid & 63, w = tid >> 6;
  const int wr = w >> 1, wc = w & 1;
  const int lr = l & 15, lk = (l >> 4) * 8;

  f32x4 acc[2][4];
#pragma unroll
  for (int m = 0; m < 2; ++m)
#pragma unroll
    for (int n = 0; n < 4; ++n) acc[m][n] = {0.f, 0.f, 0.f, 0.f};

  for (int k0 = 0; k0 < K; k0 += 32) {
    __syncthreads();
    {  // stage A: 64 rows x 32 k
      int r = tid >> 2, kq = (tid & 3) * 8;
      int gr = row0 + r;
      short8v av = {0, 0, 0, 0, 0, 0, 0, 0};
      if (gr < M) {
        if (ABF16) {
          av = *(const short8v*)((const short*)Ain + (size_t)gr * K + k0 + kq);
        } else {
          const float* ap = (const float*)Ain + (size_t)gr * K + k0 + kq;
          float4 u = *(const float4*)ap;
          float4 v = *(const float4*)(ap + 4);
          av = short8v{(short)f2bf(u.x), (short)f2bf(u.y), (short)f2bf(u.z), (short)f2bf(u.w),
                       (short)f2bf(v.x), (short)f2bf(v.y), (short)f2bf(v.z), (short)f2bf(v.w)};
        }
      }
      *(short8v*)&As[r][kq] = av;
    }
    {  // stage B: 128 cols x 32 k (Wt row-major [NC][K])
      int c = tid >> 1, kq = (tid & 1) * 8;
      const short* wp = (const short*)Wt + (size_t)(col0 + c) * K + k0 + kq;
      *(short8v*)&Bs[c][kq]      = *(const short8v*)wp;
      *(short8v*)&Bs[c][kq + 16] = *(const short8v*)(wp + 16);
    }
    __syncthreads();
    short8v a[2], b[4];
#pragma unroll
    for (int m = 0; m < 2; ++m) a[m] = *(short8v*)&As[wr * 32 + m * 16 + lr][lk];
#pragma unroll
    for (int n = 0; n < 4; ++n) b[n] = *(short8v*)&Bs[wc * 64 + n * 16 + lr][lk];
#pragma unroll
    for (int m = 0; m < 2; ++m)
#pragma unroll
      for (int n = 0; n < 4; ++n)
        acc[m][n] = __builtin_amdgcn_mfma_f32_16x16x32_bf16(a[m], b[n], acc[m][n], 0, 0, 0);
  }
  // epilogue: C/D layout col=lane&15, row=(lane>>4)*4+q
#pragma unroll
  for (int m = 0; m < 2; ++m) {
    int rbase = row0 + wr * 32 + m * 16 + (l >> 4) * 4;
#pragma unroll
    for (int n = 0; n < 4; ++n) {
      int col = col0 + wc * 64 + n * 16 + lr;
#pragma unroll
      for (int q = 0; q < 4; ++q) {
        int row = rbase + q;
        if (row < M) {
          float v = acc[m][n][q];
          Y[(size_t)row * NC + col] = v;
          Yb[(size_t)row * NC + col] = __float2bfloat16(v);
        }
      }
    }
  }
}

// ---------------- attention dots: one wave per (node,head) ----------------
__global__ __launch_bounds__(256) void sd_kernel(const float* __restrict__ H,
                                                 const float* __restrict__ As,
                                                 const float* __restrict__ Ad,
                                                 float* __restrict__ S, float* __restrict__ D,
                                                 int NB, int NH) {
  int w = blockIdx.x * 4 + (threadIdx.x >> 6);
  if (w >= NB) return;
  int lane = threadIdx.x & 63;
  int h = w % NH;
  float2 hv = reinterpret_cast<const float2*>(H + (size_t)w * 128)[lane];
  float2 as = reinterpret_cast<const float2*>(As + h * 128)[lane];
  float2 ad = reinterpret_cast<const float2*>(Ad + h * 128)[lane];
  float vs = hv.x * as.x + hv.y * as.y;
  float vd = hv.x * ad.x + hv.y * ad.y;
#pragma unroll
  for (int o = 32; o; o >>= 1) { vs += __shfl_down(vs, o); vd += __shfl_down(vd, o); }
  if (lane == 0) { S[w] = vs; D[w] = vd; }
}

// ---------------- CSR build ----------------
__global__ void deg_kernel(const int* __restrict__ edst, int E, int Etot, int* __restrict__ deg) {
  int e = blockIdx.x * blockDim.x + threadIdx.x;
  if (e >= Etot) return;
  int dn = (e < E) ? edst[e] : (e - E);
  atomicAdd(&deg[dn], 1);
}

__global__ __launch_bounds__(1024) void scan_kernel(const int* __restrict__ deg,
                                                    int* __restrict__ rowptr,
                                                    int* __restrict__ cursor, int n) {
  __shared__ int wsum[16];
  __shared__ int carry_s;
  int tid = threadIdx.x;
  int lane = tid & 63, wid = tid >> 6;
  if (tid == 0) { carry_s = 0; rowptr[0] = 0; }
  __syncthreads();
  for (int base = 0; base < n; base += 1024) {
    int i = base + tid;
    int v = (i < n) ? deg[i] : 0;
    int x = v;
#pragma unroll
    for (int o = 1; o < 64; o <<= 1) {
      int t = __shfl_up(x, o);
      if (lane >= o) x += t;
    }
    if (lane == 63) wsum[wid] = x;
    __syncthreads();
    if (wid == 0) {
      int wv = (lane < 16) ? wsum[lane] : 0;
#pragma unroll
      for (int o = 1; o < 16; o <<= 1) {
        int t = __shfl_up(wv, o);
        if (lane >= o) wv += t;
      }
      if (lane < 16) wsum[lane] = wv;
    }
    __syncthreads();
    int incl = carry_s + (wid ? wsum[wid - 1] : 0) + x;
    if (i < n) { rowptr[i + 1] = incl; cursor[i] = incl - v; }
    __syncthreads();
    if (tid == 1023) carry_s = incl;
    __syncthreads();
  }
}

__global__ void fill_kernel(const int* __restrict__ esrc, const int* __restrict__ edst,
                            int E, int Etot, int* __restrict__ cursor,
                            int* __restrict__ csr_src, int* __restrict__ csr_eid) {
  int e = blockIdx.x * blockDim.x + threadIdx.x;
  if (e >= Etot) return;
  int s, dn;
  if (e < E) { s = esrc[e]; dn = edst[e]; } else { s = dn = e - E; }
  int pos = atomicAdd(&cursor[dn], 1);
  csr_src[pos] = s;
  csr_eid[pos] = e;
}

// ---------------- agg1: fused denom + alpha-write + aggregation (zero atomics) -----------
// 192 threads (3 waves), 1 node per block. Pass A: den[h]=sum exp (block reduce).
// Pass B: recompute exp, write alpha[eid], aggregate h1b into e1b.
__global__ __launch_bounds__(192) void agg1_kernel(const __hip_bfloat16* __restrict__ h1b,
                                                   const float* __restrict__ S,
                                                   const float* __restrict__ D,
                                                   const int* __restrict__ rowptr,
                                                   const int* __restrict__ csr_src,
                                                   const int* __restrict__ csr_eid,
                                                   const float* __restrict__ b1,
                                                   __hip_bfloat16* __restrict__ e1b,
                                                   float* __restrict__ alpha_out) {
  __shared__ int lsrc[128];
  __shared__ float la[3][128];
  __shared__ float red[3][3];
  __shared__ float inv_s[3];
  int n = blockIdx.x;
  int j = threadIdx.x;           // 0..191 -> cols 2j, 2j+1
  int wid = j >> 6, lane = j & 63;
  int p0 = rowptr[n], p1 = rowptr[n + 1];
  float d0 = D[n * 3], d1 = D[n * 3 + 1], d2 = D[n * 3 + 2];

  // pass A: denom per head
  float a0 = 0.f, a1 = 0.f, a2 = 0.f;
  for (int p = p0 + j; p < p1; p += 192) {
    int sn = csr_src[p];
    a0 += __expf(lrelu(S[sn * 3] + d0));
    a1 += __expf(lrelu(S[sn * 3 + 1] + d1));
    a2 += __expf(lrelu(S[sn * 3 + 2] + d2));
  }
#pragma unroll
  for (int o = 32; o; o >>= 1) {
    a0 += __shfl_down(a0, o); a1 += __shfl_down(a1, o); a2 += __shfl_down(a2, o);
  }
  if (lane == 0) { red[wid][0] = a0; red[wid][1] = a1; red[wid][2] = a2; }
  __syncthreads();
  if (j == 0) {
    inv_s[0] = 1.f / (red[0][0] + red[1][0] + red[2][0]);
    inv_s[1] = 1.f / (red[0][1] + red[1][1] + red[2][1]);
    inv_s[2] = 1.f / (red[0][2] + red[1][2] + red[2][2]);
  }
  __syncthreads();
  float inv0 = inv_s[0], inv1 = inv_s[1], inv2 = inv_s[2];

  // pass B: alpha + aggregate
  int head = wid;
  float acc0 = 0.f, acc1 = 0.f;
  for (int base = p0; base < p1; base += 128) {
    int cnt = min(128, p1 - base);
    __syncthreads();
    if (j < cnt) {
      int sn = csr_src[base + j];
      lsrc[j] = sn;
      float e0 = __expf(lrelu(S[sn * 3] + d0)) * inv0;
      float e1 = __expf(lrelu(S[sn * 3 + 1] + d1)) * inv1;
      float e2 = __expf(lrelu(S[sn * 3 + 2] + d2)) * inv2;
      la[0][j] = e0; la[1][j] = e1; la[2][j] = e2;
      size_t eid = (size_t)csr_eid[base + j];
      alpha_out[eid * 3] = e0;
      alpha_out[eid * 3 + 1] = e1;
      alpha_out[eid * 3 + 2] = e2;
    }
    __syncthreads();
    for (int i = 0; i < cnt; ++i) {
      int sn = lsrc[i];
      float a = la[head][i];
      __hip_bfloat162 hv = reinterpret_cast<const __hip_bfloat162*>(h1b)[(size_t)sn * 192 + j];
      acc0 = fmaf(a, __bfloat162float(hv.x), acc0);
      acc1 = fmaf(a, __bfloat162float(hv.y), acc1);
    }
  }
  int c0 = 2 * j;
  float v0 = acc0 + b1[c0];
  float v1 = acc1 + b1[c0 + 1];
  __hip_bfloat162 ov;
  ov.x = __float2bfloat16(v0 > 0.f ? v0 : 0.f);
  ov.y = __float2bfloat16(v1 > 0.f ? v1 : 0.f);
  reinterpret_cast<__hip_bfloat162*>(e1b)[(size_t)n * 192 + j] = ov;
}

// ---------------- agg2: fused denom (single wave) + inline alpha + aggregation ----------
__global__ __launch_bounds__(64) void agg2_kernel(const __hip_bfloat16* __restrict__ h2b,
                                                  const float* __restrict__ S,
                                                  const float* __restrict__ D,
                                                  const int* __restrict__ rowptr,
                                                  const int* __restrict__ csr_src,
                                                  const float* __restrict__ b2,
                                                  float* __restrict__ e2out) {
  __shared__ int lsrc[128];
  __shared__ float la[128];
  int n = blockIdx.x;
  int c = threadIdx.x;           // 0..63 -> cols 2c, 2c+1
  int p0 = rowptr[n], p1 = rowptr[n + 1];
  float dn_v = D[n];

  // denom (one wave, shfl reduce + broadcast)
  float da = 0.f;
  for (int p = p0 + c; p < p1; p += 64) {
    int sn = csr_src[p];
    da += __expf(lrelu(S[sn] + dn_v));
  }
#pragma unroll
  for (int o = 32; o; o >>= 1) da += __shfl_down(da, o);
  float invden = 1.f / __shfl(da, 0);

  float acc0 = 0.f, acc1 = 0.f;
  for (int base = p0; base < p1; base += 128) {
    int cnt = min(128, p1 - base);
    __syncthreads();
    for (int i = c; i < cnt; i += 64) {
      int sn = csr_src[base + i];
      lsrc[i] = sn;
      la[i] = __expf(lrelu(S[sn] + dn_v)) * invden;
    }
    __syncthreads();
    for (int i = 0; i < cnt; ++i) {
      int sn = lsrc[i];
      float a = la[i];
      __hip_bfloat162 hv = reinterpret_cast<const __hip_bfloat162*>(h2b)[(size_t)sn * 64 + c];
      acc0 = fmaf(a, __bfloat162float(hv.x), acc0);
      acc1 = fmaf(a, __bfloat162float(hv.y), acc1);
    }
  }
  int c0 = 2 * c;
  e2out[(size_t)n * 128 + c0]     = acc0 + b2[c0];
  e2out[(size_t)n * 128 + c0 + 1] = acc1 + b2[c0 + 1];
}

// ---------------- pooling: node_attn == 1 exactly (softmax sums), so both halves = mean ------
__global__ __launch_bounds__(128) void pool_kernel(const float* __restrict__ e2,
                                                   float* __restrict__ g, int N, float invN) {
  int c = threadIdx.x;
  int r0 = blockIdx.x * 128;
  int r1 = min(r0 + 128, N);
  float acc = 0.f;
  for (int n = r0; n < r1; ++n) acc += e2[(size_t)n * 128 + c];
  acc *= invN;
  atomicAdd(&g[c], acc);
  atomicAdd(&g[128 + c], acc);
}

__global__ __launch_bounds__(256) void sim_kernel(const float* __restrict__ g1,
                                                  const float* __restrict__ g2,
                                                  float* __restrict__ out) {
  int t = threadIdx.x;
  float a = g1[t], b = g2[t];
  __shared__ float sd[256], s1[256], s2[256];
  sd[t] = a * b; s1[t] = a * a; s2[t] = b * b;
  __syncthreads();
  for (int ofs = 128; ofs; ofs >>= 1) {
    if (t < ofs) { sd[t] += sd[t + ofs]; s1[t] += s1[t + ofs]; s2[t] += s2[t + ofs]; }
    __syncthreads();
  }
  if (t == 0) {
    float n1 = fmaxf(sqrtf(s1[0]), 1e-8f);
    float n2 = fmaxf(sqrtf(s2[0]), 1e-8f);
    out[0] = sd[0] / (n1 * n2);
  }
}

// ---------------- host ----------------
extern "C" void kernel_launch(void* const* d_in, const int* in_sizes, int n_in,
                              void* d_out, int out_size, void* d_ws, size_t ws_size,
                              hipStream_t stream) {
  const int N = in_sizes[0] / INDIM;
  const int E = in_sizes[1] / 2;
  const int Etot = E + N;

  const float* W1  = (const float*)d_in[4];
  const float* as1 = (const float*)d_in[5];
  const float* ad1 = (const float*)d_in[6];
  const float* b1  = (const float*)d_in[7];
  const float* W2  = (const float*)d_in[8];
  const float* as2 = (const float*)d_in[9];
  const float* ad2 = (const float*)d_in[10];
  const float* b2  = (const float*)d_in[11];
  float* out = (float*)d_out;

  char* p = (char*)d_ws;
  auto alloc = [&](size_t bytes) -> char* {
    char* q = p;
    p += (bytes + 255) & ~(size_t)255;
    return q;
  };
  // region A: h1 (f32, N*384); e2 (N*128) aliases it (h1 dead before agg2 writes e2)
  float* h1 = (float*)alloc((size_t)N * 384 * 4);
  float* e2 = h1;
  // region B: h1b (bf16 N*384); h2 (f32 N*128) + h2b (bf16 N*128) alias it (h1b dead before gemm2)
  char* regB = alloc((size_t)N * 384 * 2);
  __hip_bfloat16* h1b = (__hip_bfloat16*)regB;
  float* h2           = (float*)regB;
  __hip_bfloat16* h2b = (__hip_bfloat16*)(regB + (size_t)N * 128 * 4);
  __hip_bfloat16* e1b = (__hip_bfloat16*)alloc((size_t)N * 384 * 2);
  __hip_bfloat16* W1t = (__hip_bfloat16*)alloc((size_t)256 * 384 * 2);
  __hip_bfloat16* W2t = (__hip_bfloat16*)alloc((size_t)384 * 128 * 2);
  float* s1v  = (float*)alloc((size_t)N * 3 * 4);
  float* d1v  = (float*)alloc((size_t)N * 3 * 4);
  float* s2v  = (float*)alloc((size_t)N * 4);
  float* d2v  = (float*)alloc((size_t)N * 4);
  float* g    = (float*)alloc(512 * 4);
  int* deg     = (int*)alloc((size_t)N * 4);
  int* rowptr  = (int*)alloc((size_t)(N + 1) * 4);
  int* cursor  = (int*)alloc((size_t)N * 4);
  int* csr_src = (int*)alloc((size_t)Etot * 4);
  int* csr_eid = (int*)alloc((size_t)Etot * 4);

  const int EB = 256;
  const int egrid = (Etot + EB - 1) / EB;
  const int gmx = (N + 63) / 64;

  hipMemsetAsync(g, 0, 512 * 4, stream);
  wprep_kernel<<<(256 * 384 + 255) / 256, 256, 0, stream>>>(W1, W1t, 256, 384, 256 * 384);
  wprep_kernel<<<(384 * 128 + 255) / 256, 256, 0, stream>>>(W2, W2t, 384, 128, 384 * 128);

  for (int b = 0; b < 2; ++b) {
    const float* x = (const float*)d_in[b ? 2 : 0];
    const int* ei = (const int*)d_in[b ? 3 : 1];
    const int* esrc = ei;
    const int* edst = ei + E;
    float* alpha1 = out + 1 + (size_t)b * (size_t)Etot * 3;

    hipMemsetAsync(deg, 0, (size_t)N * 4, stream);

    mfma_gemm<256, false><<<dim3(gmx, 3), 256, 0, stream>>>(x, W1t, h1, h1b, N, 384);
    sd_kernel<<<(N * 3 + 3) / 4, 256, 0, stream>>>(h1, as1, ad1, s1v, d1v, N * 3, 3);

    deg_kernel<<<egrid, EB, 0, stream>>>(edst, E, Etot, deg);
    scan_kernel<<<1, 1024, 0, stream>>>(deg, rowptr, cursor, N);
    fill_kernel<<<egrid, EB, 0, stream>>>(esrc, edst, E, Etot, cursor, csr_src, csr_eid);

    agg1_kernel<<<N, 192, 0, stream>>>(h1b, s1v, d1v, rowptr, csr_src, csr_eid, b1, e1b, alpha1);

    mfma_gemm<384, true><<<dim3(gmx, 1), 256, 0, stream>>>(e1b, W2t, h2, h2b, N, 128);
    sd_kernel<<<(N + 3) / 4, 256, 0, stream>>>(h2, as2, ad2, s2v, d2v, N, 1);
    agg2_kernel<<<N, 64, 0, stream>>>(h2b, s2v, d2v, rowptr, csr_src, b2, e2);

    pool_kernel<<<(N + 127) / 128, 128, 0, stream>>>(e2, g + b * 256, N, 1.f / (float)N);
  }
  sim_kernel<<<1, 256, 0, stream>>>(g, g + 256, out);
}

// Round 5
// 278.841 us; speedup vs baseline: 3.7657x; 1.3891x over previous
//
#include <hip/hip_runtime.h>
#include <hip/hip_bf16.h>
#include <cstdint>
#include <cstddef>

#define INDIM 256
#define NEG 0.2f

typedef __attribute__((ext_vector_type(8))) short short8v;
typedef __attribute__((ext_vector_type(4))) float f32x4;

__device__ __forceinline__ unsigned short f2bf(float x) {
  __hip_bfloat16 b = __float2bfloat16(x);
  return __builtin_bit_cast(unsigned short, b);
}

__device__ __forceinline__ float lrelu(float v) { return v > 0.f ? v : NEG * v; }

// ---------------- W pre-transpose to bf16: Wt[c][k] = bf16(W[k][c]) ----------------
__global__ void wprep_kernel(const float* __restrict__ W, __hip_bfloat16* __restrict__ Wt,
                             int K, int NC, int total) {
  int idx = blockIdx.x * blockDim.x + threadIdx.x;
  if (idx >= total) return;
  int k = idx / NC, c = idx - k * NC;
  Wt[(size_t)c * K + k] = __float2bfloat16(W[idx]);
}

// ---------------- MFMA GEMM over 2N batched rows: rows < Nsplit from A0, else A1 ----------
// tile 64x128, 4 waves (2x2), wave tile 32x64 = 2x4 fragments of 16x16, BK=32
template<int K, bool ABF16>
__global__ __launch_bounds__(256) void mfma_gemm(const void* __restrict__ A0,
                                                 const void* __restrict__ A1, int Nsplit,
                                                 const __hip_bfloat16* __restrict__ Wt,
                                                 float* __restrict__ Y,
                                                 __hip_bfloat16* __restrict__ Yb,
                                                 int M, int NC) {
  __shared__ short As[64][40];
  __shared__ short Bs[128][40];
  const int tid = threadIdx.x;
  const int row0 = blockIdx.x * 64;
  const int col0 = blockIdx.y * 128;
  const int l = tid & 63, w = tid >> 6;
  const int wr = w >> 1, wc = w & 1;
  const int lr = l & 15, lk = (l >> 4) * 8;

  f32x4 acc[2][4];
#pragma unroll
  for (int m = 0; m < 2; ++m)
#pragma unroll
    for (int n = 0; n < 4; ++n) acc[m][n] = {0.f, 0.f, 0.f, 0.f};

  for (int k0 = 0; k0 < K; k0 += 32) {
    __syncthreads();
    {  // stage A: 64 rows x 32 k
      int r = tid >> 2, kq = (tid & 3) * 8;
      int gr = row0 + r;
      short8v av = {0, 0, 0, 0, 0, 0, 0, 0};
      if (gr < M) {
        const void* Ab = (gr < Nsplit) ? A0 : A1;
        int lrow = (gr < Nsplit) ? gr : gr - Nsplit;
        if (ABF16) {
          av = *(const short8v*)((const short*)Ab + (size_t)lrow * K + k0 + kq);
        } else {
          const float* ap = (const float*)Ab + (size_t)lrow * K + k0 + kq;
          float4 u = *(const float4*)ap;
          float4 v = *(const float4*)(ap + 4);
          av = short8v{(short)f2bf(u.x), (short)f2bf(u.y), (short)f2bf(u.z), (short)f2bf(u.w),
                       (short)f2bf(v.x), (short)f2bf(v.y), (short)f2bf(v.z), (short)f2bf(v.w)};
        }
      }
      *(short8v*)&As[r][kq] = av;
    }
    {  // stage B: 128 cols x 32 k (Wt row-major [NC][K])
      int c = tid >> 1, kq = (tid & 1) * 8;
      const short* wp = (const short*)Wt + (size_t)(col0 + c) * K + k0 + kq;
      *(short8v*)&Bs[c][kq]      = *(const short8v*)wp;
      *(short8v*)&Bs[c][kq + 16] = *(const short8v*)(wp + 16);
    }
    __syncthreads();
    short8v a[2], b[4];
#pragma unroll
    for (int m = 0; m < 2; ++m) a[m] = *(short8v*)&As[wr * 32 + m * 16 + lr][lk];
#pragma unroll
    for (int n = 0; n < 4; ++n) b[n] = *(short8v*)&Bs[wc * 64 + n * 16 + lr][lk];
#pragma unroll
    for (int m = 0; m < 2; ++m)
#pragma unroll
      for (int n = 0; n < 4; ++n)
        acc[m][n] = __builtin_amdgcn_mfma_f32_16x16x32_bf16(a[m], b[n], acc[m][n], 0, 0, 0);
  }
  // epilogue: C/D layout col=lane&15, row=(lane>>4)*4+q
#pragma unroll
  for (int m = 0; m < 2; ++m) {
    int rbase = row0 + wr * 32 + m * 16 + (l >> 4) * 4;
#pragma unroll
    for (int n = 0; n < 4; ++n) {
      int col = col0 + wc * 64 + n * 16 + lr;
#pragma unroll
      for (int q = 0; q < 4; ++q) {
        int row = rbase + q;
        if (row < M) {
          float v = acc[m][n][q];
          Y[(size_t)row * NC + col] = v;
          Yb[(size_t)row * NC + col] = __float2bfloat16(v);
        }
      }
    }
  }
}

// ---------------- attention dots: one wave per (node2,head); node2 in [0,2N) ----------------
__global__ __launch_bounds__(256) void sd_kernel(const float* __restrict__ H,
                                                 const float* __restrict__ As,
                                                 const float* __restrict__ Ad,
                                                 float* __restrict__ S, float* __restrict__ D,
                                                 int NB, int NH) {
  int w = blockIdx.x * 4 + (threadIdx.x >> 6);
  if (w >= NB) return;
  int lane = threadIdx.x & 63;
  int h = w % NH;
  float2 hv = reinterpret_cast<const float2*>(H + (size_t)w * 128)[lane];
  float2 as = reinterpret_cast<const float2*>(As + h * 128)[lane];
  float2 ad = reinterpret_cast<const float2*>(Ad + h * 128)[lane];
  float vs = hv.x * as.x + hv.y * as.y;
  float vd = hv.x * ad.x + hv.y * ad.y;
#pragma unroll
  for (int o = 32; o; o >>= 1) { vs += __shfl_down(vs, o); vd += __shfl_down(vd, o); }
  if (lane == 0) { S[w] = vs; D[w] = vd; }
}

// ---------------- CSR build over 2N virtual nodes (both branches) ----------------
__global__ void deg_kernel(const int* __restrict__ ed1, const int* __restrict__ ed2,
                           int E, int Etot, int N, int* __restrict__ deg) {
  int idx = blockIdx.x * blockDim.x + threadIdx.x;
  if (idx >= 2 * Etot) return;
  int br = idx >= Etot;
  int el = idx - br * Etot;
  const int* ed = br ? ed2 : ed1;
  int dn = ((el < E) ? ed[el] : (el - E)) + br * N;
  atomicAdd(&deg[dn], 1);
}

__global__ __launch_bounds__(1024) void scan_kernel(const int* __restrict__ deg,
                                                    int* __restrict__ rowptr,
                                                    int* __restrict__ cursor, int n) {
  __shared__ int wsum[16];
  __shared__ int carry_s;
  int tid = threadIdx.x;
  int lane = tid & 63, wid = tid >> 6;
  if (tid == 0) { carry_s = 0; rowptr[0] = 0; }
  __syncthreads();
  for (int base = 0; base < n; base += 1024) {
    int i = base + tid;
    int v = (i < n) ? deg[i] : 0;
    int x = v;
#pragma unroll
    for (int o = 1; o < 64; o <<= 1) {
      int t = __shfl_up(x, o);
      if (lane >= o) x += t;
    }
    if (lane == 63) wsum[wid] = x;
    __syncthreads();
    if (wid == 0) {
      int wv = (lane < 16) ? wsum[lane] : 0;
#pragma unroll
      for (int o = 1; o < 16; o <<= 1) {
        int t = __shfl_up(wv, o);
        if (lane >= o) wv += t;
      }
      if (lane < 16) wsum[lane] = wv;
    }
    __syncthreads();
    int incl = carry_s + (wid ? wsum[wid - 1] : 0) + x;
    if (i < n) { rowptr[i + 1] = incl; cursor[i] = incl - v; }
    __syncthreads();
    if (tid == 1023) carry_s = incl;
    __syncthreads();
  }
}

__global__ void fill_kernel(const int* __restrict__ es1, const int* __restrict__ ed1,
                            const int* __restrict__ es2, const int* __restrict__ ed2,
                            int E, int Etot, int N, int* __restrict__ cursor,
                            int* __restrict__ csr_src) {
  int idx = blockIdx.x * blockDim.x + threadIdx.x;
  if (idx >= 2 * Etot) return;
  int br = idx >= Etot;
  int el = idx - br * Etot;
  const int* es = br ? es2 : es1;
  const int* ed = br ? ed2 : ed1;
  int sn, dn;
  if (el < E) { sn = es[el]; dn = ed[el]; } else { sn = dn = el - E; }
  sn += br * N; dn += br * N;
  int pos = atomicAdd(&cursor[dn], 1);
  csr_src[pos] = sn;
}

// ---------------- agg1: SINGLE-PASS unnormalized aggregate + inline denom ----------------
// 192 threads, 1 virtual node per block. Stage threads accumulate their own exp partials;
// block-reduce at end, scale acc by 1/den. Writes e1b (bf16) and invden per (node,head).
__global__ __launch_bounds__(192) void agg1_kernel(const __hip_bfloat16* __restrict__ h1b,
                                                   const float* __restrict__ S,
                                                   const float* __restrict__ D,
                                                   const int* __restrict__ rowptr,
                                                   const int* __restrict__ csr_src,
                                                   const float* __restrict__ b1,
                                                   __hip_bfloat16* __restrict__ e1b,
                                                   float* __restrict__ invden) {
  __shared__ int lsrc[128];
  __shared__ float la[3][128];
  __shared__ float red[3][3];
  __shared__ float inv_s[3];
  int n = blockIdx.x;
  int j = threadIdx.x;           // 0..191 -> cols 2j, 2j+1
  int wid = j >> 6, lane = j & 63;
  int p0 = rowptr[n], p1 = rowptr[n + 1];
  float d0 = D[n * 3], d1 = D[n * 3 + 1], d2 = D[n * 3 + 2];

  float dp0 = 0.f, dp1 = 0.f, dp2 = 0.f;
  float acc0 = 0.f, acc1 = 0.f;
  for (int base = p0; base < p1; base += 128) {
    int cnt = min(128, p1 - base);
    __syncthreads();
    if (j < cnt) {
      int sn = csr_src[base + j];
      lsrc[j] = sn;
      float e0 = __expf(lrelu(S[sn * 3] + d0));
      float e1 = __expf(lrelu(S[sn * 3 + 1] + d1));
      float e2 = __expf(lrelu(S[sn * 3 + 2] + d2));
      la[0][j] = e0; la[1][j] = e1; la[2][j] = e2;
      dp0 += e0; dp1 += e1; dp2 += e2;
    }
    __syncthreads();
    for (int i = 0; i < cnt; ++i) {
      int sn = lsrc[i];
      float a = la[wid][i];
      __hip_bfloat162 hv = reinterpret_cast<const __hip_bfloat162*>(h1b)[(size_t)sn * 192 + j];
      acc0 = fmaf(a, __bfloat162float(hv.x), acc0);
      acc1 = fmaf(a, __bfloat162float(hv.y), acc1);
    }
  }
  // block-reduce the exp partials
#pragma unroll
  for (int o = 32; o; o >>= 1) {
    dp0 += __shfl_down(dp0, o); dp1 += __shfl_down(dp1, o); dp2 += __shfl_down(dp2, o);
  }
  if (lane == 0) { red[wid][0] = dp0; red[wid][1] = dp1; red[wid][2] = dp2; }
  __syncthreads();
  if (j == 0) {
    inv_s[0] = 1.f / (red[0][0] + red[1][0] + red[2][0]);
    inv_s[1] = 1.f / (red[0][1] + red[1][1] + red[2][1]);
    inv_s[2] = 1.f / (red[0][2] + red[1][2] + red[2][2]);
  }
  __syncthreads();
  float inv = inv_s[wid];
  int c0 = 2 * j;
  float v0 = acc0 * inv + b1[c0];
  float v1 = acc1 * inv + b1[c0 + 1];
  __hip_bfloat162 ov;
  ov.x = __float2bfloat16(v0 > 0.f ? v0 : 0.f);
  ov.y = __float2bfloat16(v1 > 0.f ? v1 : 0.f);
  reinterpret_cast<__hip_bfloat162*>(e1b)[(size_t)n * 192 + j] = ov;
  if (j < 3) invden[n * 3 + j] = inv_s[j];
}

// ---------------- alpha: edge-major, coalesced writes into d_out ----------------
__global__ void alpha_kernel(const float* __restrict__ S, const float* __restrict__ D,
                             const float* __restrict__ invden,
                             const int* __restrict__ es1, const int* __restrict__ ed1,
                             const int* __restrict__ es2, const int* __restrict__ ed2,
                             int E, int Etot, int N, float* __restrict__ out) {
  int idx = blockIdx.x * blockDim.x + threadIdx.x;
  if (idx >= 2 * Etot) return;
  int br = idx >= Etot;
  int el = idx - br * Etot;
  const int* es = br ? es2 : es1;
  const int* ed = br ? ed2 : ed1;
  int sn, dn;
  if (el < E) { sn = es[el]; dn = ed[el]; } else { sn = dn = el - E; }
  sn += br * N; dn += br * N;
  float* ao = out + 1 + (size_t)br * Etot * 3 + (size_t)el * 3;
#pragma unroll
  for (int h = 0; h < 3; ++h) {
    float v = lrelu(S[sn * 3 + h] + D[dn * 3 + h]);
    ao[h] = __expf(v) * invden[dn * 3 + h];
  }
}

// ---------------- agg2: SINGLE-PASS, 64 threads per virtual node ----------------
__global__ __launch_bounds__(64) void agg2_kernel(const __hip_bfloat16* __restrict__ h2b,
                                                  const float* __restrict__ S,
                                                  const float* __restrict__ D,
                                                  const int* __restrict__ rowptr,
                                                  const int* __restrict__ csr_src,
                                                  const float* __restrict__ b2,
                                                  float* __restrict__ e2out) {
  __shared__ int lsrc[128];
  __shared__ float la[128];
  int n = blockIdx.x;
  int c = threadIdx.x;           // 0..63 -> cols 2c, 2c+1
  int p0 = rowptr[n], p1 = rowptr[n + 1];
  float dn_v = D[n];

  float dpart = 0.f;
  float acc0 = 0.f, acc1 = 0.f;
  for (int base = p0; base < p1; base += 128) {
    int cnt = min(128, p1 - base);
    __syncthreads();
    for (int i = c; i < cnt; i += 64) {
      int sn = csr_src[base + i];
      lsrc[i] = sn;
      float ex = __expf(lrelu(S[sn] + dn_v));
      la[i] = ex;
      dpart += ex;
    }
    __syncthreads();
    for (int i = 0; i < cnt; ++i) {
      int sn = lsrc[i];
      float a = la[i];
      __hip_bfloat162 hv = reinterpret_cast<const __hip_bfloat162*>(h2b)[(size_t)sn * 64 + c];
      acc0 = fmaf(a, __bfloat162float(hv.x), acc0);
      acc1 = fmaf(a, __bfloat162float(hv.y), acc1);
    }
  }
#pragma unroll
  for (int o = 32; o; o >>= 1) dpart += __shfl_down(dpart, o);
  float invden = 1.f / __shfl(dpart, 0);
  int c0 = 2 * c;
  e2out[(size_t)n * 128 + c0]     = acc0 * invden + b2[c0];
  e2out[(size_t)n * 128 + c0 + 1] = acc1 * invden + b2[c0 + 1];
}

// ---------------- pooling: node_attn == 1 exactly; both halves = column mean --------------
__global__ __launch_bounds__(128) void pool_kernel(const float* __restrict__ e2,
                                                   float* __restrict__ g, int N, float invN) {
  int c = threadIdx.x;
  int br = blockIdx.y;
  int r0 = br * N + blockIdx.x * 128;
  int r1 = min(r0 + 128, br * N + N);
  float acc = 0.f;
  for (int n = r0; n < r1; ++n) acc += e2[(size_t)n * 128 + c];
  acc *= invN;
  float* gb = g + (size_t)br * 256;
  atomicAdd(&gb[c], acc);
  atomicAdd(&gb[128 + c], acc);
}

__global__ __launch_bounds__(256) void sim_kernel(const float* __restrict__ g1,
                                                  const float* __restrict__ g2,
                                                  float* __restrict__ out) {
  int t = threadIdx.x;
  float a = g1[t], b = g2[t];
  __shared__ float sd[256], s1[256], s2[256];
  sd[t] = a * b; s1[t] = a * a; s2[t] = b * b;
  __syncthreads();
  for (int ofs = 128; ofs; ofs >>= 1) {
    if (t < ofs) { sd[t] += sd[t + ofs]; s1[t] += s1[t + ofs]; s2[t] += s2[t + ofs]; }
    __syncthreads();
  }
  if (t == 0) {
    float n1 = fmaxf(sqrtf(s1[0]), 1e-8f);
    float n2 = fmaxf(sqrtf(s2[0]), 1e-8f);
    out[0] = sd[0] / (n1 * n2);
  }
}

// ---------------- host ----------------
extern "C" void kernel_launch(void* const* d_in, const int* in_sizes, int n_in,
                              void* d_out, int out_size, void* d_ws, size_t ws_size,
                              hipStream_t stream) {
  const int N = in_sizes[0] / INDIM;
  const int E = in_sizes[1] / 2;
  const int Etot = E + N;
  const int N2 = 2 * N;

  const float* x1  = (const float*)d_in[0];
  const int*   ei1 = (const int*)d_in[1];
  const float* x2  = (const float*)d_in[2];
  const int*   ei2 = (const int*)d_in[3];
  const float* W1  = (const float*)d_in[4];
  const float* as1 = (const float*)d_in[5];
  const float* ad1 = (const float*)d_in[6];
  const float* b1  = (const float*)d_in[7];
  const float* W2  = (const float*)d_in[8];
  const float* as2 = (const float*)d_in[9];
  const float* ad2 = (const float*)d_in[10];
  const float* b2  = (const float*)d_in[11];
  float* out = (float*)d_out;
  const int* es1 = ei1, *ed1 = ei1 + E;
  const int* es2 = ei2, *ed2 = ei2 + E;

  char* p = (char*)d_ws;
  auto alloc = [&](size_t bytes) -> char* {
    char* q = p;
    p += (bytes + 255) & ~(size_t)255;
    return q;
  };
  float* h1           = (float*)alloc((size_t)N2 * 384 * 4);
  __hip_bfloat16* h1b = (__hip_bfloat16*)alloc((size_t)N2 * 384 * 2);
  __hip_bfloat16* e1b = (__hip_bfloat16*)alloc((size_t)N2 * 384 * 2);
  float* h2           = (float*)alloc((size_t)N2 * 128 * 4);
  __hip_bfloat16* h2b = (__hip_bfloat16*)alloc((size_t)N2 * 128 * 2);
  float* e2           = (float*)alloc((size_t)N2 * 128 * 4);
  __hip_bfloat16* W1t = (__hip_bfloat16*)alloc((size_t)256 * 384 * 2);
  __hip_bfloat16* W2t = (__hip_bfloat16*)alloc((size_t)384 * 128 * 2);
  float* s1v  = (float*)alloc((size_t)N2 * 3 * 4);
  float* d1v  = (float*)alloc((size_t)N2 * 3 * 4);
  float* s2v  = (float*)alloc((size_t)N2 * 4);
  float* d2v  = (float*)alloc((size_t)N2 * 4);
  float* idn  = (float*)alloc((size_t)N2 * 3 * 4);
  float* g    = (float*)alloc(512 * 4);
  int* deg     = (int*)alloc((size_t)N2 * 4);
  int* rowptr  = (int*)alloc((size_t)(N2 + 1) * 4);
  int* cursor  = (int*)alloc((size_t)N2 * 4);
  int* csr_src = (int*)alloc((size_t)2 * Etot * 4);

  const int EB = 256;
  const int egrid2 = (2 * Etot + EB - 1) / EB;
  const int gmx = (N2 + 63) / 64;

  hipMemsetAsync(g, 0, 512 * 4, stream);
  hipMemsetAsync(deg, 0, (size_t)N2 * 4, stream);
  wprep_kernel<<<(256 * 384 + 255) / 256, 256, 0, stream>>>(W1, W1t, 256, 384, 256 * 384);
  wprep_kernel<<<(384 * 128 + 255) / 256, 256, 0, stream>>>(W2, W2t, 384, 128, 384 * 128);

  deg_kernel<<<egrid2, EB, 0, stream>>>(ed1, ed2, E, Etot, N, deg);
  mfma_gemm<256, false><<<dim3(gmx, 3), 256, 0, stream>>>(x1, x2, N, W1t, h1, h1b, N2, 384);
  sd_kernel<<<(N2 * 3 + 3) / 4, 256, 0, stream>>>(h1, as1, ad1, s1v, d1v, N2 * 3, 3);
  scan_kernel<<<1, 1024, 0, stream>>>(deg, rowptr, cursor, N2);
  fill_kernel<<<egrid2, EB, 0, stream>>>(es1, ed1, es2, ed2, E, Etot, N, cursor, csr_src);

  agg1_kernel<<<N2, 192, 0, stream>>>(h1b, s1v, d1v, rowptr, csr_src, b1, e1b, idn);
  alpha_kernel<<<egrid2, EB, 0, stream>>>(s1v, d1v, idn, es1, ed1, es2, ed2, E, Etot, N, out);

  mfma_gemm<384, true><<<dim3(gmx, 1), 256, 0, stream>>>(e1b, e1b, N2, W2t, h2, h2b, N2, 128);
  sd_kernel<<<(N2 + 3) / 4, 256, 0, stream>>>(h2, as2, ad2, s2v, d2v, N2, 1);
  agg2_kernel<<<N2, 64, 0, stream>>>(h2b, s2v, d2v, rowptr, csr_src, b2, e2);

  pool_kernel<<<dim3((N + 127) / 128, 2), 128, 0, stream>>>(e2, g, N, 1.f / (float)N);
  sim_kernel<<<1, 256, 0, stream>>>(g, g + 256, out);
}

// Round 6
// 274.665 us; speedup vs baseline: 3.8230x; 1.0152x over previous
//
#include <hip/hip_runtime.h>
#include <hip/hip_bf16.h>
#include <cstdint>
#include <cstddef>

#define INDIM 256
#define NEG 0.2f

typedef __attribute__((ext_vector_type(8))) short short8v;
typedef __attribute__((ext_vector_type(4))) float f32x4;

__device__ __forceinline__ unsigned short f2bf(float x) {
  __hip_bfloat16 b = __float2bfloat16(x);
  return __builtin_bit_cast(unsigned short, b);
}

__device__ __forceinline__ float lrelu(float v) { return v > 0.f ? v : NEG * v; }

// ---------------- W pre-transpose to bf16: Wt[c][k] = bf16(W[k][c]) ----------------
__global__ void wprep_kernel(const float* __restrict__ W, __hip_bfloat16* __restrict__ Wt,
                             int K, int NC, int total) {
  int idx = blockIdx.x * blockDim.x + threadIdx.x;
  if (idx >= total) return;
  int k = idx / NC, c = idx - k * NC;
  Wt[(size_t)c * K + k] = __float2bfloat16(W[idx]);
}

// ---------------- MFMA GEMM over 2N batched rows: rows < Nsplit from A0, else A1 ----------
// tile 64x128, 4 waves (2x2), wave tile 32x64 = 2x4 fragments of 16x16, BK=32
template<int K, bool ABF16>
__global__ __launch_bounds__(256) void mfma_gemm(const void* __restrict__ A0,
                                                 const void* __restrict__ A1, int Nsplit,
                                                 const __hip_bfloat16* __restrict__ Wt,
                                                 float* __restrict__ Y,
                                                 __hip_bfloat16* __restrict__ Yb,
                                                 int M, int NC) {
  __shared__ short As[64][40];
  __shared__ short Bs[128][40];
  const int tid = threadIdx.x;
  const int row0 = blockIdx.x * 64;
  const int col0 = blockIdx.y * 128;
  const int l = tid & 63, w = tid >> 6;
  const int wr = w >> 1, wc = w & 1;
  const int lr = l & 15, lk = (l >> 4) * 8;

  f32x4 acc[2][4];
#pragma unroll
  for (int m = 0; m < 2; ++m)
#pragma unroll
    for (int n = 0; n < 4; ++n) acc[m][n] = {0.f, 0.f, 0.f, 0.f};

  for (int k0 = 0; k0 < K; k0 += 32) {
    __syncthreads();
    {  // stage A: 64 rows x 32 k
      int r = tid >> 2, kq = (tid & 3) * 8;
      int gr = row0 + r;
      short8v av = {0, 0, 0, 0, 0, 0, 0, 0};
      if (gr < M) {
        const void* Ab = (gr < Nsplit) ? A0 : A1;
        int lrow = (gr < Nsplit) ? gr : gr - Nsplit;
        if (ABF16) {
          av = *(const short8v*)((const short*)Ab + (size_t)lrow * K + k0 + kq);
        } else {
          const float* ap = (const float*)Ab + (size_t)lrow * K + k0 + kq;
          float4 u = *(const float4*)ap;
          float4 v = *(const float4*)(ap + 4);
          av = short8v{(short)f2bf(u.x), (short)f2bf(u.y), (short)f2bf(u.z), (short)f2bf(u.w),
                       (short)f2bf(v.x), (short)f2bf(v.y), (short)f2bf(v.z), (short)f2bf(v.w)};
        }
      }
      *(short8v*)&As[r][kq] = av;
    }
    {  // stage B: 128 cols x 32 k (Wt row-major [NC][K])
      int c = tid >> 1, kq = (tid & 1) * 8;
      const short* wp = (const short*)Wt + (size_t)(col0 + c) * K + k0 + kq;
      *(short8v*)&Bs[c][kq]      = *(const short8v*)wp;
      *(short8v*)&Bs[c][kq + 16] = *(const short8v*)(wp + 16);
    }
    __syncthreads();
    short8v a[2], b[4];
#pragma unroll
    for (int m = 0; m < 2; ++m) a[m] = *(short8v*)&As[wr * 32 + m * 16 + lr][lk];
#pragma unroll
    for (int n = 0; n < 4; ++n) b[n] = *(short8v*)&Bs[wc * 64 + n * 16 + lr][lk];
#pragma unroll
    for (int m = 0; m < 2; ++m)
#pragma unroll
      for (int n = 0; n < 4; ++n)
        acc[m][n] = __builtin_amdgcn_mfma_f32_16x16x32_bf16(a[m], b[n], acc[m][n], 0, 0, 0);
  }
  // epilogue: C/D layout col=lane&15, row=(lane>>4)*4+q
#pragma unroll
  for (int m = 0; m < 2; ++m) {
    int rbase = row0 + wr * 32 + m * 16 + (l >> 4) * 4;
#pragma unroll
    for (int n = 0; n < 4; ++n) {
      int col = col0 + wc * 64 + n * 16 + lr;
#pragma unroll
      for (int q = 0; q < 4; ++q) {
        int row = rbase + q;
        if (row < M) {
          float v = acc[m][n][q];
          Y[(size_t)row * NC + col] = v;
          Yb[(size_t)row * NC + col] = __float2bfloat16(v);
        }
      }
    }
  }
}

// ---------------- attention dots: one wave per (node2,head); node2 in [0,2N) ----------------
__global__ __launch_bounds__(256) void sd_kernel(const float* __restrict__ H,
                                                 const float* __restrict__ As,
                                                 const float* __restrict__ Ad,
                                                 float* __restrict__ S, float* __restrict__ D,
                                                 int NB, int NH) {
  int w = blockIdx.x * 4 + (threadIdx.x >> 6);
  if (w >= NB) return;
  int lane = threadIdx.x & 63;
  int h = w % NH;
  float2 hv = reinterpret_cast<const float2*>(H + (size_t)w * 128)[lane];
  float2 as = reinterpret_cast<const float2*>(As + h * 128)[lane];
  float2 ad = reinterpret_cast<const float2*>(Ad + h * 128)[lane];
  float vs = hv.x * as.x + hv.y * as.y;
  float vd = hv.x * ad.x + hv.y * ad.y;
#pragma unroll
  for (int o = 32; o; o >>= 1) { vs += __shfl_down(vs, o); vd += __shfl_down(vd, o); }
  if (lane == 0) { S[w] = vs; D[w] = vd; }
}

// ---------------- CSR build over 2N virtual nodes (both branches) ----------------
__global__ void deg_kernel(const int* __restrict__ ed1, const int* __restrict__ ed2,
                           int E, int Etot, int N, int* __restrict__ deg) {
  int idx = blockIdx.x * blockDim.x + threadIdx.x;
  if (idx >= 2 * Etot) return;
  int br = idx >= Etot;
  int el = idx - br * Etot;
  const int* ed = br ? ed2 : ed1;
  int dn = ((el < E) ? ed[el] : (el - E)) + br * N;
  atomicAdd(&deg[dn], 1);
}

__global__ __launch_bounds__(1024) void scan_kernel(const int* __restrict__ deg,
                                                    int* __restrict__ rowptr,
                                                    int* __restrict__ cursor, int n) {
  __shared__ int wsum[16];
  __shared__ int carry_s;
  int tid = threadIdx.x;
  int lane = tid & 63, wid = tid >> 6;
  if (tid == 0) { carry_s = 0; rowptr[0] = 0; }
  __syncthreads();
  for (int base = 0; base < n; base += 1024) {
    int i = base + tid;
    int v = (i < n) ? deg[i] : 0;
    int x = v;
#pragma unroll
    for (int o = 1; o < 64; o <<= 1) {
      int t = __shfl_up(x, o);
      if (lane >= o) x += t;
    }
    if (lane == 63) wsum[wid] = x;
    __syncthreads();
    if (wid == 0) {
      int wv = (lane < 16) ? wsum[lane] : 0;
#pragma unroll
      for (int o = 1; o < 16; o <<= 1) {
        int t = __shfl_up(wv, o);
        if (lane >= o) wv += t;
      }
      if (lane < 16) wsum[lane] = wv;
    }
    __syncthreads();
    int incl = carry_s + (wid ? wsum[wid - 1] : 0) + x;
    if (i < n) { rowptr[i + 1] = incl; cursor[i] = incl - v; }
    __syncthreads();
    if (tid == 1023) carry_s = incl;
    __syncthreads();
  }
}

__global__ void fill_kernel(const int* __restrict__ es1, const int* __restrict__ ed1,
                            const int* __restrict__ es2, const int* __restrict__ ed2,
                            int E, int Etot, int N, int* __restrict__ cursor,
                            int* __restrict__ csr_src) {
  int idx = blockIdx.x * blockDim.x + threadIdx.x;
  if (idx >= 2 * Etot) return;
  int br = idx >= Etot;
  int el = idx - br * Etot;
  const int* es = br ? es2 : es1;
  const int* ed = br ? ed2 : ed1;
  int sn, dn;
  if (el < E) { sn = es[el]; dn = ed[el]; } else { sn = dn = el - E; }
  sn += br * N; dn += br * N;
  int pos = atomicAdd(&cursor[dn], 1);
  csr_src[pos] = sn;
}

// ---------------- agg1: SINGLE-PASS unnormalized aggregate + inline denom ----------------
// 192 threads, 1 virtual node per block. 8x unrolled prefetch on the gather loop (ILP).
__global__ __launch_bounds__(192) void agg1_kernel(const __hip_bfloat16* __restrict__ h1b,
                                                   const float* __restrict__ S,
                                                   const float* __restrict__ D,
                                                   const int* __restrict__ rowptr,
                                                   const int* __restrict__ csr_src,
                                                   const float* __restrict__ b1,
                                                   __hip_bfloat16* __restrict__ e1b,
                                                   float* __restrict__ invden) {
  __shared__ int lsrc[192];
  __shared__ float la[3][192];
  __shared__ float red[3][3];
  __shared__ float inv_s[3];
  const __hip_bfloat162* H2 = reinterpret_cast<const __hip_bfloat162*>(h1b);
  int n = blockIdx.x;
  int j = threadIdx.x;           // 0..191 -> cols 2j, 2j+1
  int wid = j >> 6, lane = j & 63;
  int p0 = rowptr[n], p1 = rowptr[n + 1];
  float d0 = D[n * 3], d1 = D[n * 3 + 1], d2 = D[n * 3 + 2];

  float dp0 = 0.f, dp1 = 0.f, dp2 = 0.f;
  float acc0 = 0.f, acc1 = 0.f;
  for (int base = p0; base < p1; base += 192) {
    int cnt = min(192, p1 - base);
    __syncthreads();
    if (j < cnt) {
      int sn = csr_src[base + j];
      lsrc[j] = sn;
      float e0 = __expf(lrelu(S[sn * 3] + d0));
      float e1 = __expf(lrelu(S[sn * 3 + 1] + d1));
      float e2 = __expf(lrelu(S[sn * 3 + 2] + d2));
      la[0][j] = e0; la[1][j] = e1; la[2][j] = e2;
      dp0 += e0; dp1 += e1; dp2 += e2;
    }
    __syncthreads();
    int i = 0;
    for (; i + 8 <= cnt; i += 8) {
      float av[8];
      __hip_bfloat162 hv[8];
#pragma unroll
      for (int u = 0; u < 8; ++u) {
        int sn = lsrc[i + u];
        av[u] = la[wid][i + u];
        hv[u] = H2[(size_t)sn * 192 + j];
      }
#pragma unroll
      for (int u = 0; u < 8; ++u) {
        acc0 = fmaf(av[u], __bfloat162float(hv[u].x), acc0);
        acc1 = fmaf(av[u], __bfloat162float(hv[u].y), acc1);
      }
    }
    for (; i < cnt; ++i) {
      int sn = lsrc[i];
      float a = la[wid][i];
      __hip_bfloat162 hv = H2[(size_t)sn * 192 + j];
      acc0 = fmaf(a, __bfloat162float(hv.x), acc0);
      acc1 = fmaf(a, __bfloat162float(hv.y), acc1);
    }
  }
  // block-reduce the exp partials
#pragma unroll
  for (int o = 32; o; o >>= 1) {
    dp0 += __shfl_down(dp0, o); dp1 += __shfl_down(dp1, o); dp2 += __shfl_down(dp2, o);
  }
  if (lane == 0) { red[wid][0] = dp0; red[wid][1] = dp1; red[wid][2] = dp2; }
  __syncthreads();
  if (j == 0) {
    inv_s[0] = 1.f / (red[0][0] + red[1][0] + red[2][0]);
    inv_s[1] = 1.f / (red[0][1] + red[1][1] + red[2][1]);
    inv_s[2] = 1.f / (red[0][2] + red[1][2] + red[2][2]);
  }
  __syncthreads();
  float inv = inv_s[wid];
  int c0 = 2 * j;
  float v0 = acc0 * inv + b1[c0];
  float v1 = acc1 * inv + b1[c0 + 1];
  __hip_bfloat162 ov;
  ov.x = __float2bfloat16(v0 > 0.f ? v0 : 0.f);
  ov.y = __float2bfloat16(v1 > 0.f ? v1 : 0.f);
  reinterpret_cast<__hip_bfloat162*>(e1b)[(size_t)n * 192 + j] = ov;
  if (j < 3) invden[n * 3 + j] = inv_s[j];
}

// ---------------- alpha: edge-major, coalesced writes into d_out ----------------
__global__ void alpha_kernel(const float* __restrict__ S, const float* __restrict__ D,
                             const float* __restrict__ invden,
                             const int* __restrict__ es1, const int* __restrict__ ed1,
                             const int* __restrict__ es2, const int* __restrict__ ed2,
                             int E, int Etot, int N, float* __restrict__ out) {
  int idx = blockIdx.x * blockDim.x + threadIdx.x;
  if (idx >= 2 * Etot) return;
  int br = idx >= Etot;
  int el = idx - br * Etot;
  const int* es = br ? es2 : es1;
  const int* ed = br ? ed2 : ed1;
  int sn, dn;
  if (el < E) { sn = es[el]; dn = ed[el]; } else { sn = dn = el - E; }
  sn += br * N; dn += br * N;
  float* ao = out + 1 + (size_t)br * Etot * 3 + (size_t)el * 3;
#pragma unroll
  for (int h = 0; h < 3; ++h) {
    float v = lrelu(S[sn * 3 + h] + D[dn * 3 + h]);
    ao[h] = __expf(v) * invden[dn * 3 + h];
  }
}

// ---------------- agg2: SINGLE-PASS, 64 threads per virtual node, 8x unrolled ------------
__global__ __launch_bounds__(64) void agg2_kernel(const __hip_bfloat16* __restrict__ h2b,
                                                  const float* __restrict__ S,
                                                  const float* __restrict__ D,
                                                  const int* __restrict__ rowptr,
                                                  const int* __restrict__ csr_src,
                                                  const float* __restrict__ b2,
                                                  float* __restrict__ e2out) {
  __shared__ int lsrc[256];
  __shared__ float la[256];
  const __hip_bfloat162* H2 = reinterpret_cast<const __hip_bfloat162*>(h2b);
  int n = blockIdx.x;
  int c = threadIdx.x;           // 0..63 -> cols 2c, 2c+1
  int p0 = rowptr[n], p1 = rowptr[n + 1];
  float dn_v = D[n];

  float dpart = 0.f;
  float acc0 = 0.f, acc1 = 0.f;
  for (int base = p0; base < p1; base += 256) {
    int cnt = min(256, p1 - base);
    __syncthreads();
    for (int i = c; i < cnt; i += 64) {
      int sn = csr_src[base + i];
      lsrc[i] = sn;
      float ex = __expf(lrelu(S[sn] + dn_v));
      la[i] = ex;
      dpart += ex;
    }
    __syncthreads();
    int i = 0;
    for (; i + 8 <= cnt; i += 8) {
      float av[8];
      __hip_bfloat162 hv[8];
#pragma unroll
      for (int u = 0; u < 8; ++u) {
        int sn = lsrc[i + u];
        av[u] = la[i + u];
        hv[u] = H2[(size_t)sn * 64 + c];
      }
#pragma unroll
      for (int u = 0; u < 8; ++u) {
        acc0 = fmaf(av[u], __bfloat162float(hv[u].x), acc0);
        acc1 = fmaf(av[u], __bfloat162float(hv[u].y), acc1);
      }
    }
    for (; i < cnt; ++i) {
      int sn = lsrc[i];
      float a = la[i];
      __hip_bfloat162 hv = H2[(size_t)sn * 64 + c];
      acc0 = fmaf(a, __bfloat162float(hv.x), acc0);
      acc1 = fmaf(a, __bfloat162float(hv.y), acc1);
    }
  }
#pragma unroll
  for (int o = 32; o; o >>= 1) dpart += __shfl_down(dpart, o);
  float invden = 1.f / __shfl(dpart, 0);
  int c0 = 2 * c;
  e2out[(size_t)n * 128 + c0]     = acc0 * invden + b2[c0];
  e2out[(size_t)n * 128 + c0 + 1] = acc1 * invden + b2[c0 + 1];
}

// ---------------- pooling: node_attn == 1 exactly; both halves = column mean --------------
__global__ __launch_bounds__(128) void pool_kernel(const float* __restrict__ e2,
                                                   float* __restrict__ g, int N, float invN) {
  int c = threadIdx.x;
  int br = blockIdx.y;
  int r0 = br * N + blockIdx.x * 128;
  int r1 = min(r0 + 128, br * N + N);
  float acc = 0.f;
  for (int n = r0; n < r1; ++n) acc += e2[(size_t)n * 128 + c];
  acc *= invN;
  float* gb = g + (size_t)br * 256;
  atomicAdd(&gb[c], acc);
  atomicAdd(&gb[128 + c], acc);
}

__global__ __launch_bounds__(256) void sim_kernel(const float* __restrict__ g1,
                                                  const float* __restrict__ g2,
                                                  float* __restrict__ out) {
  int t = threadIdx.x;
  float a = g1[t], b = g2[t];
  __shared__ float sd[256], s1[256], s2[256];
  sd[t] = a * b; s1[t] = a * a; s2[t] = b * b;
  __syncthreads();
  for (int ofs = 128; ofs; ofs >>= 1) {
    if (t < ofs) { sd[t] += sd[t + ofs]; s1[t] += s1[t + ofs]; s2[t] += s2[t + ofs]; }
    __syncthreads();
  }
  if (t == 0) {
    float n1 = fmaxf(sqrtf(s1[0]), 1e-8f);
    float n2 = fmaxf(sqrtf(s2[0]), 1e-8f);
    out[0] = sd[0] / (n1 * n2);
  }
}

// ---------------- host ----------------
extern "C" void kernel_launch(void* const* d_in, const int* in_sizes, int n_in,
                              void* d_out, int out_size, void* d_ws, size_t ws_size,
                              hipStream_t stream) {
  const int N = in_sizes[0] / INDIM;
  const int E = in_sizes[1] / 2;
  const int Etot = E + N;
  const int N2 = 2 * N;

  const float* x1  = (const float*)d_in[0];
  const int*   ei1 = (const int*)d_in[1];
  const float* x2  = (const float*)d_in[2];
  const int*   ei2 = (const int*)d_in[3];
  const float* W1  = (const float*)d_in[4];
  const float* as1 = (const float*)d_in[5];
  const float* ad1 = (const float*)d_in[6];
  const float* b1  = (const float*)d_in[7];
  const float* W2  = (const float*)d_in[8];
  const float* as2 = (const float*)d_in[9];
  const float* ad2 = (const float*)d_in[10];
  const float* b2  = (const float*)d_in[11];
  float* out = (float*)d_out;
  const int* es1 = ei1, *ed1 = ei1 + E;
  const int* es2 = ei2, *ed2 = ei2 + E;

  char* p = (char*)d_ws;
  auto alloc = [&](size_t bytes) -> char* {
    char* q = p;
    p += (bytes + 255) & ~(size_t)255;
    return q;
  };
  float* h1           = (float*)alloc((size_t)N2 * 384 * 4);
  __hip_bfloat16* h1b = (__hip_bfloat16*)alloc((size_t)N2 * 384 * 2);
  __hip_bfloat16* e1b = (__hip_bfloat16*)alloc((size_t)N2 * 384 * 2);
  float* h2           = (float*)alloc((size_t)N2 * 128 * 4);
  __hip_bfloat16* h2b = (__hip_bfloat16*)alloc((size_t)N2 * 128 * 2);
  float* e2           = (float*)alloc((size_t)N2 * 128 * 4);
  __hip_bfloat16* W1t = (__hip_bfloat16*)alloc((size_t)256 * 384 * 2);
  __hip_bfloat16* W2t = (__hip_bfloat16*)alloc((size_t)384 * 128 * 2);
  float* s1v  = (float*)alloc((size_t)N2 * 3 * 4);
  float* d1v  = (float*)alloc((size_t)N2 * 3 * 4);
  float* s2v  = (float*)alloc((size_t)N2 * 4);
  float* d2v  = (float*)alloc((size_t)N2 * 4);
  float* idn  = (float*)alloc((size_t)N2 * 3 * 4);
  float* g    = (float*)alloc(512 * 4);
  int* deg     = (int*)alloc((size_t)N2 * 4);
  int* rowptr  = (int*)alloc((size_t)(N2 + 1) * 4);
  int* cursor  = (int*)alloc((size_t)N2 * 4);
  int* csr_src = (int*)alloc((size_t)2 * Etot * 4);

  const int EB = 256;
  const int egrid2 = (2 * Etot + EB - 1) / EB;
  const int gmx = (N2 + 63) / 64;

  hipMemsetAsync(g, 0, 512 * 4, stream);
  hipMemsetAsync(deg, 0, (size_t)N2 * 4, stream);
  wprep_kernel<<<(256 * 384 + 255) / 256, 256, 0, stream>>>(W1, W1t, 256, 384, 256 * 384);
  wprep_kernel<<<(384 * 128 + 255) / 256, 256, 0, stream>>>(W2, W2t, 384, 128, 384 * 128);

  deg_kernel<<<egrid2, EB, 0, stream>>>(ed1, ed2, E, Etot, N, deg);
  mfma_gemm<256, false><<<dim3(gmx, 3), 256, 0, stream>>>(x1, x2, N, W1t, h1, h1b, N2, 384);
  sd_kernel<<<(N2 * 3 + 3) / 4, 256, 0, stream>>>(h1, as1, ad1, s1v, d1v, N2 * 3, 3);
  scan_kernel<<<1, 1024, 0, stream>>>(deg, rowptr, cursor, N2);
  fill_kernel<<<egrid2, EB, 0, stream>>>(es1, ed1, es2, ed2, E, Etot, N, cursor, csr_src);

  agg1_kernel<<<N2, 192, 0, stream>>>(h1b, s1v, d1v, rowptr, csr_src, b1, e1b, idn);
  alpha_kernel<<<egrid2, EB, 0, stream>>>(s1v, d1v, idn, es1, ed1, es2, ed2, E, Etot, N, out);

  mfma_gemm<384, true><<<dim3(gmx, 1), 256, 0, stream>>>(e1b, e1b, N2, W2t, h2, h2b, N2, 128);
  sd_kernel<<<(N2 + 3) / 4, 256, 0, stream>>>(h2, as2, ad2, s2v, d2v, N2, 1);
  agg2_kernel<<<N2, 64, 0, stream>>>(h2b, s2v, d2v, rowptr, csr_src, b2, e2);

  pool_kernel<<<dim3((N + 127) / 128, 2), 128, 0, stream>>>(e2, g, N, 1.f / (float)N);
  sim_kernel<<<1, 256, 0, stream>>>(g, g + 256, out);
}